// Round 13
// baseline (254.337 us; speedup 1.0000x reference)
//
#include <hip/hip_runtime.h>
#include <math.h>

// Problem constants (fixed by the reference)
constexpr int B     = 8;
constexpr int N_PER = 2048;
constexpr int C     = 256;
constexpr int KG    = 16;
constexpr int KTOP  = 512;
constexpr int KNN   = 32;
constexpr int N     = B * N_PER;   // 16384
constexpr float EPS = 1e-5f;

typedef __attribute__((ext_vector_type(8))) short  short8;   // 8 bf16 (4 VGPRs)
typedef __attribute__((ext_vector_type(4))) float  f32x4;    // MFMA acc frag

// ---------------------------------------------------------------------------
// Exact 3-way bf16 split: f = h + m + l + O(2^-27 |f|); subtractions exact.
// ---------------------------------------------------------------------------
__device__ inline void split3(float f, unsigned short& h, unsigned short& m,
                              unsigned short& l)
{
    const unsigned u  = __float_as_uint(f);
    const unsigned r1 = (u + 0x7FFFu + ((u >> 16) & 1u)) & 0xFFFF0000u;
    h = (unsigned short)(r1 >> 16);
    const float f2 = f - __uint_as_float(r1);
    const unsigned u2 = __float_as_uint(f2);
    const unsigned r2 = (u2 + 0x7FFFu + ((u2 >> 16) & 1u)) & 0xFFFF0000u;
    m = (unsigned short)(r2 >> 16);
    const float f3 = f2 - __uint_as_float(r2);
    const unsigned u3 = __float_as_uint(f3);
    l = (unsigned short)((u3 + 0x7FFFu + ((u3 >> 16) & 1u)) >> 16);
}

__device__ inline void cvt_store24(unsigned short* dh, unsigned short* dm,
                                   unsigned short* dl, float4 a, float4 b)
{
    short8 h, m, l;
    unsigned short hh, mm, ll;
    float v[8] = {a.x, a.y, a.z, a.w, b.x, b.y, b.z, b.w};
#pragma unroll
    for (int j = 0; j < 8; ++j) {
        split3(v[j], hh, mm, ll);
        h[j] = (short)hh;
        m[j] = (short)mm;
        l[j] = (short)ll;
    }
    *(short8*)dh = h;
    *(short8*)dm = m;
    *(short8*)dl = l;
}

__device__ inline void split8v(const float* __restrict__ s,
                               unsigned short* __restrict__ dh,
                               unsigned short* __restrict__ dm,
                               unsigned short* __restrict__ dl)
{
    float4 a = *(const float4*)s;
    float4 b = *(const float4*)(s + 4);
    float v[8] = {a.x, a.y, a.z, a.w, b.x, b.y, b.z, b.w};
    short8 h8, m8, l8;
    unsigned short hh, mm, ll;
#pragma unroll
    for (int j = 0; j < 8; ++j) {
        split3(v[j], hh, mm, ll);
        h8[j] = (short)hh;
        m8[j] = (short)mm;
        l8[j] = (short)ll;
    }
    *(short8*)dh = h8;
    *(short8*)dm = m8;
    *(short8*)dl = l8;
}

// ---------------------------------------------------------------------------
// K0w: split ONLY the weights into bf16 h/m/l planes (786KB, ~3us).
// ---------------------------------------------------------------------------
constexpr int GW = C * C / 8;    // 8192 groups per weight matrix

__global__ __launch_bounds__(256) void k0w_split(
    const float* __restrict__ thw, const float* __restrict__ phw,
    unsigned short* __restrict__ th, unsigned short* __restrict__ tm,
    unsigned short* __restrict__ tl,
    unsigned short* __restrict__ ph, unsigned short* __restrict__ pm,
    unsigned short* __restrict__ pl)
{
    const int g = blockIdx.x * 256 + threadIdx.x;
    if (g < GW) {
        const int o = g * 8;
        split8v(thw + o, th + o, tm + o, tl + o);
    } else if (g < 2 * GW) {
        const int o = (g - GW) * 8;
        split8v(phw + o, ph + o, pm + o, pl + o);
    }
}

// ---------------------------------------------------------------------------
// K1 (R9 kernel, PASS at 44.0us): R5 LDS/MFMA skeleton + weight planes.
// NUMERICS BIT-IDENTICAL to the R5/R9 PASS.
// ---------------------------------------------------------------------------
__global__ __launch_bounds__(256) void k1_wp(
    const float* __restrict__ x,
    const unsigned short* __restrict__ th, const unsigned short* __restrict__ tm,
    const unsigned short* __restrict__ tl,
    const unsigned short* __restrict__ ph, const unsigned short* __restrict__ pm,
    const unsigned short* __restrict__ pl,
    const float* __restrict__ thb, const float* __restrict__ phb,
    float* __restrict__ T, float* __restrict__ R)
{
    constexpr int BM = 128, BN = 64, ST = 40;
    __shared__ unsigned short sA[3][BM * ST];
    __shared__ unsigned short sT[3][BN * ST];
    __shared__ unsigned short sP[3][BN * ST];

    const int tid  = threadIdx.x;
    const int row0 = blockIdx.x * BM;
    const int n0   = blockIdx.y * BN;
    const int lane = tid & 63;
    const int wv   = tid >> 6;
    const int wr   = (wv >> 1) * 64;
    const int wc   = (wv & 1) * 32;
    const int fr   = lane & 15;
    const int fk   = (lane >> 4) * 8;
    const int ar0  = tid >> 2;            // staging row 0..63
    const int ac   = (tid & 3) * 8;       // staging k-chunk

    f32x4 acTh[4][2], acTl[4][2], acQh[4][2], acQl[4][2];
    const f32x4 zz = {0.f, 0.f, 0.f, 0.f};
#pragma unroll
    for (int m = 0; m < 4; ++m)
#pragma unroll
        for (int n = 0; n < 2; ++n) {
            acTh[m][n] = zz; acTl[m][n] = zz;
            acQh[m][n] = zz; acQl[m][n] = zz;
        }

    const float* xA0 = x + (size_t)(row0 + ar0)      * C + ac;
    const float* xA1 = x + (size_t)(row0 + 64 + ar0) * C + ac;
    const size_t offW = (size_t)(n0 + ar0) * C + ac;

    float4 a0a = *(const float4*)(xA0 + 0), a0b = *(const float4*)(xA0 + 4);
    float4 a1a = *(const float4*)(xA1 + 0), a1b = *(const float4*)(xA1 + 4);
    short8 rTh = *(const short8*)(th + offW);
    short8 rTm = *(const short8*)(tm + offW);
    short8 rTl = *(const short8*)(tl + offW);
    short8 rPh = *(const short8*)(ph + offW);
    short8 rPm = *(const short8*)(pm + offW);
    short8 rPl = *(const short8*)(pl + offW);

    const int sOffA0 = ar0 * ST + ac;
    const int sOffA1 = (64 + ar0) * ST + ac;
    const int aBase  = (wr + fr) * ST + fk;
    const int bBase  = (wc + fr) * ST + fk;

    for (int step = 0; step < 8; ++step) {
        __syncthreads();
        cvt_store24(sA[0] + sOffA0, sA[1] + sOffA0, sA[2] + sOffA0, a0a, a0b);
        cvt_store24(sA[0] + sOffA1, sA[1] + sOffA1, sA[2] + sOffA1, a1a, a1b);
        *(short8*)(sT[0] + sOffA0) = rTh;
        *(short8*)(sT[1] + sOffA0) = rTm;
        *(short8*)(sT[2] + sOffA0) = rTl;
        *(short8*)(sP[0] + sOffA0) = rPh;
        *(short8*)(sP[1] + sOffA0) = rPm;
        *(short8*)(sP[2] + sOffA0) = rPl;
        __syncthreads();

        if (step < 7) {
            const int kn = (step + 1) * 32;
            a0a = *(const float4*)(xA0 + kn); a0b = *(const float4*)(xA0 + kn + 4);
            a1a = *(const float4*)(xA1 + kn); a1b = *(const float4*)(xA1 + kn + 4);
            rTh = *(const short8*)(th + offW + kn);
            rTm = *(const short8*)(tm + offW + kn);
            rTl = *(const short8*)(tl + offW + kn);
            rPh = *(const short8*)(ph + offW + kn);
            rPm = *(const short8*)(pm + offW + kn);
            rPl = *(const short8*)(pl + offW + kn);
        }

        short8 a1f[4], a2f[4], a3f[4];
#pragma unroll
        for (int m = 0; m < 4; ++m) {
            const int r = aBase + m * 16 * ST;
            a1f[m] = *(const short8*)(sA[0] + r);
            a2f[m] = *(const short8*)(sA[1] + r);
            a3f[m] = *(const short8*)(sA[2] + r);
        }
        {
            short8 t0[2], p0[2];
#pragma unroll
            for (int n = 0; n < 2; ++n) {
                const int r = bBase + n * 16 * ST;
                t0[n] = *(const short8*)(sT[0] + r);
                p0[n] = *(const short8*)(sP[0] + r);
            }
#pragma unroll
            for (int m = 0; m < 4; ++m)
#pragma unroll
                for (int n = 0; n < 2; ++n) {
                    acTh[m][n] = __builtin_amdgcn_mfma_f32_16x16x32_bf16(a1f[m], t0[n], acTh[m][n], 0, 0, 0);
                    acQh[m][n] = __builtin_amdgcn_mfma_f32_16x16x32_bf16(a1f[m], p0[n], acQh[m][n], 0, 0, 0);
                    acTl[m][n] = __builtin_amdgcn_mfma_f32_16x16x32_bf16(a2f[m], t0[n], acTl[m][n], 0, 0, 0);
                    acQl[m][n] = __builtin_amdgcn_mfma_f32_16x16x32_bf16(a2f[m], p0[n], acQl[m][n], 0, 0, 0);
                    acTl[m][n] = __builtin_amdgcn_mfma_f32_16x16x32_bf16(a3f[m], t0[n], acTl[m][n], 0, 0, 0);
                    acQl[m][n] = __builtin_amdgcn_mfma_f32_16x16x32_bf16(a3f[m], p0[n], acQl[m][n], 0, 0, 0);
                }
        }
        {
            short8 t1[2], p1[2];
#pragma unroll
            for (int n = 0; n < 2; ++n) {
                const int r = bBase + n * 16 * ST;
                t1[n] = *(const short8*)(sT[1] + r);
                p1[n] = *(const short8*)(sP[1] + r);
            }
#pragma unroll
            for (int m = 0; m < 4; ++m)
#pragma unroll
                for (int n = 0; n < 2; ++n) {
                    acTl[m][n] = __builtin_amdgcn_mfma_f32_16x16x32_bf16(a1f[m], t1[n], acTl[m][n], 0, 0, 0);
                    acQl[m][n] = __builtin_amdgcn_mfma_f32_16x16x32_bf16(a1f[m], p1[n], acQl[m][n], 0, 0, 0);
                    acTl[m][n] = __builtin_amdgcn_mfma_f32_16x16x32_bf16(a2f[m], t1[n], acTl[m][n], 0, 0, 0);
                    acQl[m][n] = __builtin_amdgcn_mfma_f32_16x16x32_bf16(a2f[m], p1[n], acQl[m][n], 0, 0, 0);
                }
        }
        {
            short8 t2[2], p2[2];
#pragma unroll
            for (int n = 0; n < 2; ++n) {
                const int r = bBase + n * 16 * ST;
                t2[n] = *(const short8*)(sT[2] + r);
                p2[n] = *(const short8*)(sP[2] + r);
            }
#pragma unroll
            for (int m = 0; m < 4; ++m)
#pragma unroll
                for (int n = 0; n < 2; ++n) {
                    acTl[m][n] = __builtin_amdgcn_mfma_f32_16x16x32_bf16(a1f[m], t2[n], acTl[m][n], 0, 0, 0);
                    acQl[m][n] = __builtin_amdgcn_mfma_f32_16x16x32_bf16(a1f[m], p2[n], acQl[m][n], 0, 0, 0);
                }
        }
    }

    const int cr = (lane >> 4) * 4;
#pragma unroll
    for (int m = 0; m < 4; ++m) {
#pragma unroll
        for (int n = 0; n < 2; ++n) {
            const int col  = n0 + wc + n * 16 + fr;
            const float bias = thb[col] + phb[col];
#pragma unroll
            for (int j = 0; j < 4; ++j) {
                const int row = row0 + wr + m * 16 + cr + j;
                const size_t off = (size_t)row * C + col;
                const float tval = acTh[m][n][j] + acTl[m][n][j];
                const float qval = acQh[m][n][j] + acQl[m][n][j];
                T[off] = tval;
                R[off] = x[off] + qval + bias - tval;
            }
        }
    }
}

// ---------------------------------------------------------------------------
// K1 FALLBACK (R5 kernel): if ws can't hold weight planes.
// ---------------------------------------------------------------------------
__global__ __launch_bounds__(256) void k1_fb(
    const float* __restrict__ x, const float* __restrict__ thw,
    const float* __restrict__ phw, const float* __restrict__ thb,
    const float* __restrict__ phb, float* __restrict__ T, float* __restrict__ R)
{
    constexpr int BM = 128, BN = 64, ST = 40;
    __shared__ unsigned short sA[3][BM * ST];
    __shared__ unsigned short sT[3][BN * ST];
    __shared__ unsigned short sP[3][BN * ST];

    const int tid  = threadIdx.x;
    const int row0 = blockIdx.x * BM;
    const int n0   = blockIdx.y * BN;
    const int lane = tid & 63;
    const int wv   = tid >> 6;
    const int wr   = (wv >> 1) * 64;
    const int wc   = (wv & 1) * 32;
    const int fr   = lane & 15;
    const int fk   = (lane >> 4) * 8;
    const int ar0 = tid >> 2;
    const int ac  = (tid & 3) * 8;

    f32x4 acTh[4][2], acTl[4][2], acQh[4][2], acQl[4][2];
    const f32x4 zz = {0.f, 0.f, 0.f, 0.f};
#pragma unroll
    for (int m = 0; m < 4; ++m)
#pragma unroll
        for (int n = 0; n < 2; ++n) {
            acTh[m][n] = zz; acTl[m][n] = zz;
            acQh[m][n] = zz; acQl[m][n] = zz;
        }

    const float* xA0 = x   + (size_t)(row0 + ar0)      * C + ac;
    const float* xA1 = x   + (size_t)(row0 + 64 + ar0) * C + ac;
    const float* wT  = thw + (size_t)(n0 + ar0)        * C + ac;
    const float* wP  = phw + (size_t)(n0 + ar0)        * C + ac;

    float4 a0a = *(const float4*)(xA0 + 0), a0b = *(const float4*)(xA0 + 4);
    float4 a1a = *(const float4*)(xA1 + 0), a1b = *(const float4*)(xA1 + 4);
    float4 ta  = *(const float4*)(wT  + 0), tb_ = *(const float4*)(wT  + 4);
    float4 pa  = *(const float4*)(wP  + 0), pb_ = *(const float4*)(wP  + 4);

    const int sOffA0 = ar0 * ST + ac;
    const int sOffA1 = (64 + ar0) * ST + ac;
    const int aBase  = (wr + fr) * ST + fk;
    const int bBase  = (wc + fr) * ST + fk;

    for (int step = 0; step < 8; ++step) {
        __syncthreads();
        cvt_store24(sA[0] + sOffA0, sA[1] + sOffA0, sA[2] + sOffA0, a0a, a0b);
        cvt_store24(sA[0] + sOffA1, sA[1] + sOffA1, sA[2] + sOffA1, a1a, a1b);
        cvt_store24(sT[0] + sOffA0, sT[1] + sOffA0, sT[2] + sOffA0, ta,  tb_);
        cvt_store24(sP[0] + sOffA0, sP[1] + sOffA0, sP[2] + sOffA0, pa,  pb_);
        __syncthreads();

        if (step < 7) {
            const int kn = (step + 1) * 32;
            a0a = *(const float4*)(xA0 + kn); a0b = *(const float4*)(xA0 + kn + 4);
            a1a = *(const float4*)(xA1 + kn); a1b = *(const float4*)(xA1 + kn + 4);
            ta  = *(const float4*)(wT  + kn); tb_ = *(const float4*)(wT  + kn + 4);
            pa  = *(const float4*)(wP  + kn); pb_ = *(const float4*)(wP  + kn + 4);
        }

        short8 a1f[4], a2f[4], a3f[4];
#pragma unroll
        for (int m = 0; m < 4; ++m) {
            const int r = aBase + m * 16 * ST;
            a1f[m] = *(const short8*)(sA[0] + r);
            a2f[m] = *(const short8*)(sA[1] + r);
            a3f[m] = *(const short8*)(sA[2] + r);
        }
        {
            short8 t0[2], p0[2];
#pragma unroll
            for (int n = 0; n < 2; ++n) {
                const int r = bBase + n * 16 * ST;
                t0[n] = *(const short8*)(sT[0] + r);
                p0[n] = *(const short8*)(sP[0] + r);
            }
#pragma unroll
            for (int m = 0; m < 4; ++m)
#pragma unroll
                for (int n = 0; n < 2; ++n) {
                    acTh[m][n] = __builtin_amdgcn_mfma_f32_16x16x32_bf16(a1f[m], t0[n], acTh[m][n], 0, 0, 0);
                    acQh[m][n] = __builtin_amdgcn_mfma_f32_16x16x32_bf16(a1f[m], p0[n], acQh[m][n], 0, 0, 0);
                    acTl[m][n] = __builtin_amdgcn_mfma_f32_16x16x32_bf16(a2f[m], t0[n], acTl[m][n], 0, 0, 0);
                    acQl[m][n] = __builtin_amdgcn_mfma_f32_16x16x32_bf16(a2f[m], p0[n], acQl[m][n], 0, 0, 0);
                    acTl[m][n] = __builtin_amdgcn_mfma_f32_16x16x32_bf16(a3f[m], t0[n], acTl[m][n], 0, 0, 0);
                    acQl[m][n] = __builtin_amdgcn_mfma_f32_16x16x32_bf16(a3f[m], p0[n], acQl[m][n], 0, 0, 0);
                }
        }
        {
            short8 t1[2], p1[2];
#pragma unroll
            for (int n = 0; n < 2; ++n) {
                const int r = bBase + n * 16 * ST;
                t1[n] = *(const short8*)(sT[1] + r);
                p1[n] = *(const short8*)(sP[1] + r);
            }
#pragma unroll
            for (int m = 0; m < 4; ++m)
#pragma unroll
                for (int n = 0; n < 2; ++n) {
                    acTl[m][n] = __builtin_amdgcn_mfma_f32_16x16x32_bf16(a1f[m], t1[n], acTl[m][n], 0, 0, 0);
                    acQl[m][n] = __builtin_amdgcn_mfma_f32_16x16x32_bf16(a1f[m], p1[n], acQl[m][n], 0, 0, 0);
                    acTl[m][n] = __builtin_amdgcn_mfma_f32_16x16x32_bf16(a2f[m], t1[n], acTl[m][n], 0, 0, 0);
                    acQl[m][n] = __builtin_amdgcn_mfma_f32_16x16x32_bf16(a2f[m], p1[n], acQl[m][n], 0, 0, 0);
                }
        }
        {
            short8 t2[2], p2[2];
#pragma unroll
            for (int n = 0; n < 2; ++n) {
                const int r = bBase + n * 16 * ST;
                t2[n] = *(const short8*)(sT[2] + r);
                p2[n] = *(const short8*)(sP[2] + r);
            }
#pragma unroll
            for (int m = 0; m < 4; ++m)
#pragma unroll
                for (int n = 0; n < 2; ++n) {
                    acTl[m][n] = __builtin_amdgcn_mfma_f32_16x16x32_bf16(a1f[m], t2[n], acTl[m][n], 0, 0, 0);
                    acQl[m][n] = __builtin_amdgcn_mfma_f32_16x16x32_bf16(a1f[m], p2[n], acQl[m][n], 0, 0, 0);
                }
        }
    }

    const int cr = (lane >> 4) * 4;
#pragma unroll
    for (int m = 0; m < 4; ++m) {
#pragma unroll
        for (int n = 0; n < 2; ++n) {
            const int col  = n0 + wc + n * 16 + fr;
            const float bias = thb[col] + phb[col];
#pragma unroll
            for (int j = 0; j < 4; ++j) {
                const int row = row0 + wr + m * 16 + cr + j;
                const size_t off = (size_t)row * C + col;
                const float tval = acTh[m][n][j] + acTl[m][n][j];
                const float qval = acQh[m][n][j] + acQl[m][n][j];
                T[off] = tval;
                R[off] = x[off] + qval + bias - tval;
            }
        }
    }
}

// ---------------------------------------------------------------------------
// K2ab (FUSED k2a + k2bc): phase 1 = per-block gather-max (x1 = R + max_k T,
// k2a's exact per-wave float4 pattern, same fmax order) -> x1 global (L1-hot
// for phase 2, still needed by k5); phase 2 = verbatim k2bc score MLP reading
// x1 back through L1/L2. Removes one kernel boundary + the 16MB HBM x1
// round-trip. blockIdx&7 = batch -> XCD keeps each XCD's 2MB T-slab
// L2-resident under round-robin dispatch. 64 nodes/block, grid N/64=256.
// All accumulation orders identical to the R12 PASS -> bit-identical scores.
// ---------------------------------------------------------------------------
__global__ __launch_bounds__(256) void k2ab_fused(
    const int* __restrict__ esrc, const float* __restrict__ T,
    float* __restrict__ x1,
    const float* __restrict__ w1, const float* __restrict__ b1,
    const float* __restrict__ g1, const float* __restrict__ be1,
    const float* __restrict__ m1, const float* __restrict__ v1,
    const float* __restrict__ w2, const float* __restrict__ b2,
    const float* __restrict__ g2, const float* __restrict__ be2,
    const float* __restrict__ m2, const float* __restrict__ v2,
    const float* __restrict__ w3, const float* __restrict__ b3,
    float* __restrict__ score_ws, float* __restrict__ out_score)
{
    constexpr int BK = 16, ST = 68;
    __shared__ float Xs[BK * ST];
    __shared__ float Ws[BK * ST];
    __shared__ float t1s[64 * 65];
    __shared__ float w2s[32 * 65];
    __shared__ float w3s[32];
    __shared__ float zs[64 * 33];
    __shared__ int eidx[64][KG];

    const int tid  = threadIdx.x;
    const int bb   = blockIdx.x & 7;                       // batch -> XCD
    const int row0 = bb * N_PER + (blockIdx.x >> 3) * 64;

    // ---- phase 0: stage edge lists (64 nodes x 16 edges) ----
#pragma unroll
    for (int q = 0; q < 4; ++q) {
        const int i = tid + q * 256;
        eidx[i >> 4][i & 15] = esrc[(row0 + (i >> 4)) * KG + (i & 15)];
    }
    __syncthreads();

    // ---- phase 1: gather-max + R -> x1 (k2a's exact pattern/order) ----
    {
        const int w = tid >> 6, c4 = (tid & 63) * 4;
        for (int it = 0; it < 16; ++it) {
            const int nl = w * 16 + it;
            const int g  = row0 + nl;
            float4 acc = make_float4(-INFINITY, -INFINITY, -INFINITY, -INFINITY);
#pragma unroll
            for (int k = 0; k < KG; ++k) {
                const float4 v = *(const float4*)&T[(size_t)eidx[nl][k] * C + c4];
                acc.x = fmaxf(acc.x, v.x);  acc.y = fmaxf(acc.y, v.y);
                acc.z = fmaxf(acc.z, v.z);  acc.w = fmaxf(acc.w, v.w);
            }
            const size_t off = (size_t)g * C + c4;
            float4 r = *(const float4*)&x1[off];
            r.x += acc.x;  r.y += acc.y;  r.z += acc.z;  r.w += acc.w;
            *(float4*)&x1[off] = r;
        }
    }
    __syncthreads();

    // ---- phase 2: verbatim k2bc body (reads x1 back: L1/L2 hit) ----
    const int tx = tid & 15, ty = tid >> 4;
    const int lm = tid >> 2, lq = (tid & 3) << 2;

    float acc[4][4] = {{0.f}};
    for (int k0 = 0; k0 < C; k0 += BK) {
        float4 fx = *(const float4*)(x1 + (size_t)(row0 + lm) * C + k0 + lq);
        float4 fw = *(const float4*)(w1 + (size_t)lm * C + k0 + lq);
        __syncthreads();
        Xs[(lq + 0) * ST + lm] = fx.x;  Xs[(lq + 1) * ST + lm] = fx.y;
        Xs[(lq + 2) * ST + lm] = fx.z;  Xs[(lq + 3) * ST + lm] = fx.w;
        Ws[(lq + 0) * ST + lm] = fw.x;  Ws[(lq + 1) * ST + lm] = fw.y;
        Ws[(lq + 2) * ST + lm] = fw.z;  Ws[(lq + 3) * ST + lm] = fw.w;
        __syncthreads();
#pragma unroll
        for (int k = 0; k < BK; ++k) {
            float4 a4 = *(const float4*)&Xs[k * ST + (ty << 2)];
            float4 w4 = *(const float4*)&Ws[k * ST + (tx << 2)];
            float av[4] = {a4.x, a4.y, a4.z, a4.w};
            float wv[4] = {w4.x, w4.y, w4.z, w4.w};
#pragma unroll
            for (int i2 = 0; i2 < 4; ++i2)
#pragma unroll
                for (int j2 = 0; j2 < 4; ++j2) acc[i2][j2] += av[i2] * wv[j2];
        }
    }
    __syncthreads();
#pragma unroll
    for (int i2 = 0; i2 < 4; ++i2) {
        const int mrow = (ty << 2) + i2;
#pragma unroll
        for (int j2 = 0; j2 < 4; ++j2) {
            const int o = (tx << 2) + j2;
            float y = acc[i2][j2] + b1[o];
            y = fmaxf(y, 0.f);
            y = (y - m1[o]) * (1.0f / sqrtf(v1[o] + EPS)) * g1[o] + be1[o];
            t1s[mrow * 65 + o] = y;
        }
    }
    for (int idx = tid; idx < 2048; idx += 256)
        w2s[(idx >> 6) * 65 + (idx & 63)] = w2[idx];
    if (tid < 32) w3s[tid] = w3[tid];
    __syncthreads();

    const int o = tid & 31;
    const float inv2 = (1.0f / sqrtf(v2[o] + EPS)) * g2[o];
#pragma unroll
    for (int p = 0; p < 8; ++p) {
        const int nl = p * 8 + (tid >> 5);
        float z = 0.f;
#pragma unroll
        for (int j = 0; j < 64; ++j) z += t1s[nl * 65 + j] * w2s[o * 65 + j];
        z += b2[o];
        z = fmaxf(z, 0.f);
        z = (z - m2[o]) * inv2 + be2[o];
        zs[nl * 33 + o] = z;
    }
    __syncthreads();

    if (tid < 64) {
        float sacc = 0.f;
#pragma unroll
        for (int j = 0; j < 32; ++j) sacc += zs[tid * 33 + j] * w3s[j];
        sacc += b3[0];
        const int node = row0 + tid;
        score_ws[node]  = sacc;
        out_score[node] = sacc;
    }
}

// ---------------------------------------------------------------------------
// K3 (rank-select): per-batch top-512, bit-identical to the bitonic version.
// ---------------------------------------------------------------------------
__global__ __launch_bounds__(256) void k3_rank(
    const float* __restrict__ score, const float* __restrict__ xyz,
    float* __restrict__ out_topk, int* __restrict__ perm,
    float* __restrict__ xsel)
{
    __shared__ unsigned long long keys[N_PER];  // 16 KB
    const int b   = blockIdx.x >> 3;
    const int seg = blockIdx.x & 7;
    const int t   = threadIdx.x;
    for (int i = t; i < N_PER; i += 256) {
        const float v = score[b * N_PER + i];
        unsigned u = __float_as_uint(v);
        const unsigned ua = (u & 0x80000000u) ? ~u : (u | 0x80000000u);
        const unsigned ud = ~ua;   // descending-monotone
        keys[i] = ((unsigned long long)ud << 32) | (unsigned)i;
    }
    __syncthreads();
    const int i = seg * 256 + t;
    const unsigned long long k = keys[i];
    int r = 0;
#pragma unroll 8
    for (int j = 0; j < N_PER; ++j) r += (keys[j] < k) ? 1 : 0;
    if (r < KTOP) {
        const int g = b * N_PER + i;
        const int o = b * KTOP + r;
        out_topk[o] = score[g];
        perm[o] = g;
        xsel[o * 3 + 0] = xyz[g * 3 + 0];
        xsel[o * 3 + 1] = xyz[g * 3 + 1];
        xsel[o * 3 + 2] = xyz[g * 3 + 2];
    }
}

// ---------------------------------------------------------------------------
// K5 (wave merge-extract): fused gather + 32-NN, bit-identical output order.
// ---------------------------------------------------------------------------
__device__ inline unsigned long long shfl_xor_u64(unsigned long long v, int m)
{
    unsigned lo = (unsigned)v, hi = (unsigned)(v >> 32);
    lo = __shfl_xor(lo, m, 64);
    hi = __shfl_xor(hi, m, 64);
    return ((unsigned long long)hi << 32) | lo;
}

__global__ __launch_bounds__(256) void k5_rank(
    const int* __restrict__ perm, const float* __restrict__ xsel,
    const float* __restrict__ x1, const float* __restrict__ xorig,
    float* __restrict__ out_xnew, float* __restrict__ out_xcopy,
    float* __restrict__ out_knn)
{
    constexpr int G = 4;
    __shared__ float px[KTOP], py[KTOP], pz[KTOP];
    const int t  = threadIdx.x;
    const int q0 = blockIdx.x * G;
    const int b  = q0 >> 9;
    const int i0 = q0 & 511;

    for (int idx = t; idx < KTOP; idx += 256) {
        const size_t base = ((size_t)b * KTOP + idx) * 3;
        px[idx] = xsel[base + 0];
        py[idx] = xsel[base + 1];
        pz[idx] = xsel[base + 2];
    }
#pragma unroll
    for (int p = 0; p < G; ++p) {
        const int row = q0 + p;
        const int g = perm[row];
        out_xnew [(size_t)row * C + t] = x1   [(size_t)g * C + t];
        out_xcopy[(size_t)row * C + t] = xorig[(size_t)g * C + t];
    }
    __syncthreads();

    const int w    = t >> 6;          // wave id = query slot
    const int lane = t & 63;
    const int q    = i0 + w;          // query index within 512
    const float qx = px[q], qy = py[q], qz = pz[q];

    unsigned long long arr[8];
#pragma unroll
    for (int e = 0; e < 8; ++e) {
        const int j = lane + 64 * e;  // stride-64: conflict-free LDS reads
        const float dx = __fsub_rn(qx, px[j]);
        const float dy = __fsub_rn(qy, py[j]);
        const float dz = __fsub_rn(qz, pz[j]);
        const float d2 = __fadd_rn(__fadd_rn(__fmul_rn(dx, dx), __fmul_rn(dy, dy)),
                                   __fmul_rn(dz, dz));
        arr[e] = ((unsigned long long)__float_as_uint(d2) << 32) | (unsigned)j;
    }
    // sort 8 ascending, fully-unrolled bubble network (const indices -> regs)
#pragma unroll
    for (int pass = 0; pass < 7; ++pass)
#pragma unroll
        for (int i = 0; i < 7; ++i) {
            if (i < 7 - pass) {
                const unsigned long long a = arr[i], c = arr[i + 1];
                arr[i]     = (a < c) ? a : c;
                arr[i + 1] = (a < c) ? c : a;
            }
        }
    // 32 rounds of wave-min merge-extract
    float* dst = out_knn + (size_t)(q0 + w) * KNN;
    for (int r = 0; r < KNN; ++r) {
        unsigned long long m = arr[0];
#pragma unroll
        for (int off = 32; off; off >>= 1) {
            const unsigned long long o = shfl_xor_u64(m, off);
            m = (o < m) ? o : m;
        }
        if (arr[0] == m) {            // unique winner (keys contain idx)
            dst[r] = (float)(unsigned)(m & 0xffffffffu);
#pragma unroll
            for (int i = 0; i < 7; ++i) arr[i] = arr[i + 1];
            arr[7] = ~0ull;           // sentinel
        }
    }
}

// ---------------------------------------------------------------------------
extern "C" void kernel_launch(void* const* d_in, const int* in_sizes, int n_in,
                              void* d_out, int out_size, void* d_ws, size_t ws_size,
                              hipStream_t stream)
{
    const float* x     = (const float*)d_in[0];
    const float* xorig = (const float*)d_in[1];
    const float* xyz   = (const float*)d_in[2];
    const int*   esrc  = (const int*)d_in[3];
    const float* thw = (const float*)d_in[5];
    const float* thb = (const float*)d_in[6];
    const float* phw = (const float*)d_in[7];
    const float* phb = (const float*)d_in[8];
    const float* w1  = (const float*)d_in[9];
    const float* b1  = (const float*)d_in[10];
    const float* g1  = (const float*)d_in[11];
    const float* be1 = (const float*)d_in[12];
    const float* m1  = (const float*)d_in[13];
    const float* v1  = (const float*)d_in[14];
    const float* w2  = (const float*)d_in[15];
    const float* b2  = (const float*)d_in[16];
    const float* g2  = (const float*)d_in[17];
    const float* be2 = (const float*)d_in[18];
    const float* m2  = (const float*)d_in[19];
    const float* v2  = (const float*)d_in[20];
    const float* w3  = (const float*)d_in[21];
    const float* b3  = (const float*)d_in[22];

    float* ws   = (float*)d_ws;
    float* T    = ws;                          // N*C
    float* x1   = ws + (size_t)N * C;          // N*C  (R from k1, becomes x1)
    float* sc   = ws + 2 * (size_t)N * C;      // N
    int*   perm = (int*)(sc + N);              // B*KTOP
    float* xsel = (float*)(perm + B * KTOP);   // B*KTOP*3

    // weight split planes (bf16), 16B-aligned by construction
    unsigned short* th = (unsigned short*)(xsel + (size_t)B * KTOP * 3);
    unsigned short* tm = th + (size_t)C * C;
    unsigned short* tl = tm + (size_t)C * C;
    unsigned short* ph = tl + (size_t)C * C;
    unsigned short* pm = ph + (size_t)C * C;
    unsigned short* pl = pm + (size_t)C * C;
    const size_t ws_need = (size_t)((char*)(pl + (size_t)C * C) - (char*)ws);
    const bool planes_ok = (ws_size >= ws_need);

    float* out     = (float*)d_out;
    float* o_knn   = out;                                  // B*KTOP*KNN
    float* o_xnew  = o_knn + (size_t)B * KTOP * KNN;       // B*KTOP*C
    float* o_xcopy = o_xnew + (size_t)B * KTOP * C;        // B*KTOP*C
    float* o_score = o_xcopy + (size_t)B * KTOP * C;       // B*N_PER
    float* o_topk  = o_score + (size_t)B * N_PER;          // B*KTOP

    if (planes_ok) {
        k0w_split<<<(2 * GW + 255) / 256, 256, 0, stream>>>(
            thw, phw, th, tm, tl, ph, pm, pl);
        k1_wp<<<dim3(N / 128, C / 64), 256, 0, stream>>>(
            x, th, tm, tl, ph, pm, pl, thb, phb, T, x1);
    } else {
        k1_fb<<<dim3(N / 128, C / 64), 256, 0, stream>>>(x, thw, phw, thb, phb, T, x1);
    }
    k2ab_fused<<<N / 64, 256, 0, stream>>>(esrc, T, x1,
                                           w1, b1, g1, be1, m1, v1,
                                           w2, b2, g2, be2, m2, v2, w3, b3,
                                           sc, o_score);
    k3_rank<<<8 * B, 256, 0, stream>>>(sc, xyz, o_topk, perm, xsel);
    k5_rank<<<B * KTOP / 4, 256, 0, stream>>>(perm, xsel, x1, xorig,
                                              o_xnew, o_xcopy, o_knn);
}

// Round 14
// 242.730 us; speedup vs baseline: 1.0478x; 1.0478x over previous
//
#include <hip/hip_runtime.h>
#include <math.h>

// Problem constants (fixed by the reference)
constexpr int B     = 8;
constexpr int N_PER = 2048;
constexpr int C     = 256;
constexpr int KG    = 16;
constexpr int KTOP  = 512;
constexpr int KNN   = 32;
constexpr int N     = B * N_PER;   // 16384
constexpr float EPS = 1e-5f;

typedef __attribute__((ext_vector_type(8))) short  short8;   // 8 bf16 (4 VGPRs)
typedef __attribute__((ext_vector_type(4))) float  f32x4;    // MFMA acc frag

// ---------------------------------------------------------------------------
// Exact 3-way bf16 split: f = h + m + l + O(2^-27 |f|); subtractions exact.
// ---------------------------------------------------------------------------
__device__ inline void split3(float f, unsigned short& h, unsigned short& m,
                              unsigned short& l)
{
    const unsigned u  = __float_as_uint(f);
    const unsigned r1 = (u + 0x7FFFu + ((u >> 16) & 1u)) & 0xFFFF0000u;
    h = (unsigned short)(r1 >> 16);
    const float f2 = f - __uint_as_float(r1);
    const unsigned u2 = __float_as_uint(f2);
    const unsigned r2 = (u2 + 0x7FFFu + ((u2 >> 16) & 1u)) & 0xFFFF0000u;
    m = (unsigned short)(r2 >> 16);
    const float f3 = f2 - __uint_as_float(r2);
    const unsigned u3 = __float_as_uint(f3);
    l = (unsigned short)((u3 + 0x7FFFu + ((u3 >> 16) & 1u)) >> 16);
}

__device__ inline void cvt_store24(unsigned short* dh, unsigned short* dm,
                                   unsigned short* dl, float4 a, float4 b)
{
    short8 h, m, l;
    unsigned short hh, mm, ll;
    float v[8] = {a.x, a.y, a.z, a.w, b.x, b.y, b.z, b.w};
#pragma unroll
    for (int j = 0; j < 8; ++j) {
        split3(v[j], hh, mm, ll);
        h[j] = (short)hh;
        m[j] = (short)mm;
        l[j] = (short)ll;
    }
    *(short8*)dh = h;
    *(short8*)dm = m;
    *(short8*)dl = l;
}

__device__ inline void split8v(const float* __restrict__ s,
                               unsigned short* __restrict__ dh,
                               unsigned short* __restrict__ dm,
                               unsigned short* __restrict__ dl)
{
    float4 a = *(const float4*)s;
    float4 b = *(const float4*)(s + 4);
    float v[8] = {a.x, a.y, a.z, a.w, b.x, b.y, b.z, b.w};
    short8 h8, m8, l8;
    unsigned short hh, mm, ll;
#pragma unroll
    for (int j = 0; j < 8; ++j) {
        split3(v[j], hh, mm, ll);
        h8[j] = (short)hh;
        m8[j] = (short)mm;
        l8[j] = (short)ll;
    }
    *(short8*)dh = h8;
    *(short8*)dm = m8;
    *(short8*)dl = l8;
}

// ---------------------------------------------------------------------------
// K0w: split ONLY the weights into bf16 h/m/l planes (786KB, ~3us).
// ---------------------------------------------------------------------------
constexpr int GW = C * C / 8;    // 8192 groups per weight matrix

__global__ __launch_bounds__(256) void k0w_split(
    const float* __restrict__ thw, const float* __restrict__ phw,
    unsigned short* __restrict__ th, unsigned short* __restrict__ tm,
    unsigned short* __restrict__ tl,
    unsigned short* __restrict__ ph, unsigned short* __restrict__ pm,
    unsigned short* __restrict__ pl)
{
    const int g = blockIdx.x * 256 + threadIdx.x;
    if (g < GW) {
        const int o = g * 8;
        split8v(thw + o, th + o, tm + o, tl + o);
    } else if (g < 2 * GW) {
        const int o = (g - GW) * 8;
        split8v(phw + o, ph + o, pm + o, pl + o);
    }
}

// ---------------------------------------------------------------------------
// K1 (R9 kernel, PASS at 44.0us): R5 LDS/MFMA skeleton + weight planes.
// NUMERICS BIT-IDENTICAL to the R5/R9 PASS.
// ---------------------------------------------------------------------------
__global__ __launch_bounds__(256) void k1_wp(
    const float* __restrict__ x,
    const unsigned short* __restrict__ th, const unsigned short* __restrict__ tm,
    const unsigned short* __restrict__ tl,
    const unsigned short* __restrict__ ph, const unsigned short* __restrict__ pm,
    const unsigned short* __restrict__ pl,
    const float* __restrict__ thb, const float* __restrict__ phb,
    float* __restrict__ T, float* __restrict__ R)
{
    constexpr int BM = 128, BN = 64, ST = 40;
    __shared__ unsigned short sA[3][BM * ST];
    __shared__ unsigned short sT[3][BN * ST];
    __shared__ unsigned short sP[3][BN * ST];

    const int tid  = threadIdx.x;
    const int row0 = blockIdx.x * BM;
    const int n0   = blockIdx.y * BN;
    const int lane = tid & 63;
    const int wv   = tid >> 6;
    const int wr   = (wv >> 1) * 64;
    const int wc   = (wv & 1) * 32;
    const int fr   = lane & 15;
    const int fk   = (lane >> 4) * 8;
    const int ar0  = tid >> 2;            // staging row 0..63
    const int ac   = (tid & 3) * 8;       // staging k-chunk

    f32x4 acTh[4][2], acTl[4][2], acQh[4][2], acQl[4][2];
    const f32x4 zz = {0.f, 0.f, 0.f, 0.f};
#pragma unroll
    for (int m = 0; m < 4; ++m)
#pragma unroll
        for (int n = 0; n < 2; ++n) {
            acTh[m][n] = zz; acTl[m][n] = zz;
            acQh[m][n] = zz; acQl[m][n] = zz;
        }

    const float* xA0 = x + (size_t)(row0 + ar0)      * C + ac;
    const float* xA1 = x + (size_t)(row0 + 64 + ar0) * C + ac;
    const size_t offW = (size_t)(n0 + ar0) * C + ac;

    float4 a0a = *(const float4*)(xA0 + 0), a0b = *(const float4*)(xA0 + 4);
    float4 a1a = *(const float4*)(xA1 + 0), a1b = *(const float4*)(xA1 + 4);
    short8 rTh = *(const short8*)(th + offW);
    short8 rTm = *(const short8*)(tm + offW);
    short8 rTl = *(const short8*)(tl + offW);
    short8 rPh = *(const short8*)(ph + offW);
    short8 rPm = *(const short8*)(pm + offW);
    short8 rPl = *(const short8*)(pl + offW);

    const int sOffA0 = ar0 * ST + ac;
    const int sOffA1 = (64 + ar0) * ST + ac;
    const int aBase  = (wr + fr) * ST + fk;
    const int bBase  = (wc + fr) * ST + fk;

    for (int step = 0; step < 8; ++step) {
        __syncthreads();
        cvt_store24(sA[0] + sOffA0, sA[1] + sOffA0, sA[2] + sOffA0, a0a, a0b);
        cvt_store24(sA[0] + sOffA1, sA[1] + sOffA1, sA[2] + sOffA1, a1a, a1b);
        *(short8*)(sT[0] + sOffA0) = rTh;
        *(short8*)(sT[1] + sOffA0) = rTm;
        *(short8*)(sT[2] + sOffA0) = rTl;
        *(short8*)(sP[0] + sOffA0) = rPh;
        *(short8*)(sP[1] + sOffA0) = rPm;
        *(short8*)(sP[2] + sOffA0) = rPl;
        __syncthreads();

        if (step < 7) {
            const int kn = (step + 1) * 32;
            a0a = *(const float4*)(xA0 + kn); a0b = *(const float4*)(xA0 + kn + 4);
            a1a = *(const float4*)(xA1 + kn); a1b = *(const float4*)(xA1 + kn + 4);
            rTh = *(const short8*)(th + offW + kn);
            rTm = *(const short8*)(tm + offW + kn);
            rTl = *(const short8*)(tl + offW + kn);
            rPh = *(const short8*)(ph + offW + kn);
            rPm = *(const short8*)(pm + offW + kn);
            rPl = *(const short8*)(pl + offW + kn);
        }

        short8 a1f[4], a2f[4], a3f[4];
#pragma unroll
        for (int m = 0; m < 4; ++m) {
            const int r = aBase + m * 16 * ST;
            a1f[m] = *(const short8*)(sA[0] + r);
            a2f[m] = *(const short8*)(sA[1] + r);
            a3f[m] = *(const short8*)(sA[2] + r);
        }
        {
            short8 t0[2], p0[2];
#pragma unroll
            for (int n = 0; n < 2; ++n) {
                const int r = bBase + n * 16 * ST;
                t0[n] = *(const short8*)(sT[0] + r);
                p0[n] = *(const short8*)(sP[0] + r);
            }
#pragma unroll
            for (int m = 0; m < 4; ++m)
#pragma unroll
                for (int n = 0; n < 2; ++n) {
                    acTh[m][n] = __builtin_amdgcn_mfma_f32_16x16x32_bf16(a1f[m], t0[n], acTh[m][n], 0, 0, 0);
                    acQh[m][n] = __builtin_amdgcn_mfma_f32_16x16x32_bf16(a1f[m], p0[n], acQh[m][n], 0, 0, 0);
                    acTl[m][n] = __builtin_amdgcn_mfma_f32_16x16x32_bf16(a2f[m], t0[n], acTl[m][n], 0, 0, 0);
                    acQl[m][n] = __builtin_amdgcn_mfma_f32_16x16x32_bf16(a2f[m], p0[n], acQl[m][n], 0, 0, 0);
                    acTl[m][n] = __builtin_amdgcn_mfma_f32_16x16x32_bf16(a3f[m], t0[n], acTl[m][n], 0, 0, 0);
                    acQl[m][n] = __builtin_amdgcn_mfma_f32_16x16x32_bf16(a3f[m], p0[n], acQl[m][n], 0, 0, 0);
                }
        }
        {
            short8 t1[2], p1[2];
#pragma unroll
            for (int n = 0; n < 2; ++n) {
                const int r = bBase + n * 16 * ST;
                t1[n] = *(const short8*)(sT[1] + r);
                p1[n] = *(const short8*)(sP[1] + r);
            }
#pragma unroll
            for (int m = 0; m < 4; ++m)
#pragma unroll
                for (int n = 0; n < 2; ++n) {
                    acTl[m][n] = __builtin_amdgcn_mfma_f32_16x16x32_bf16(a1f[m], t1[n], acTl[m][n], 0, 0, 0);
                    acQl[m][n] = __builtin_amdgcn_mfma_f32_16x16x32_bf16(a1f[m], p1[n], acQl[m][n], 0, 0, 0);
                    acTl[m][n] = __builtin_amdgcn_mfma_f32_16x16x32_bf16(a2f[m], t1[n], acTl[m][n], 0, 0, 0);
                    acQl[m][n] = __builtin_amdgcn_mfma_f32_16x16x32_bf16(a2f[m], p1[n], acQl[m][n], 0, 0, 0);
                }
        }
        {
            short8 t2[2], p2[2];
#pragma unroll
            for (int n = 0; n < 2; ++n) {
                const int r = bBase + n * 16 * ST;
                t2[n] = *(const short8*)(sT[2] + r);
                p2[n] = *(const short8*)(sP[2] + r);
            }
#pragma unroll
            for (int m = 0; m < 4; ++m)
#pragma unroll
                for (int n = 0; n < 2; ++n) {
                    acTl[m][n] = __builtin_amdgcn_mfma_f32_16x16x32_bf16(a1f[m], t2[n], acTl[m][n], 0, 0, 0);
                    acQl[m][n] = __builtin_amdgcn_mfma_f32_16x16x32_bf16(a1f[m], p2[n], acQl[m][n], 0, 0, 0);
                }
        }
    }

    const int cr = (lane >> 4) * 4;
#pragma unroll
    for (int m = 0; m < 4; ++m) {
#pragma unroll
        for (int n = 0; n < 2; ++n) {
            const int col  = n0 + wc + n * 16 + fr;
            const float bias = thb[col] + phb[col];
#pragma unroll
            for (int j = 0; j < 4; ++j) {
                const int row = row0 + wr + m * 16 + cr + j;
                const size_t off = (size_t)row * C + col;
                const float tval = acTh[m][n][j] + acTl[m][n][j];
                const float qval = acQh[m][n][j] + acQl[m][n][j];
                T[off] = tval;
                R[off] = x[off] + qval + bias - tval;
            }
        }
    }
}

// ---------------------------------------------------------------------------
// K1 FALLBACK (R5 kernel): if ws can't hold weight planes.
// ---------------------------------------------------------------------------
__global__ __launch_bounds__(256) void k1_fb(
    const float* __restrict__ x, const float* __restrict__ thw,
    const float* __restrict__ phw, const float* __restrict__ thb,
    const float* __restrict__ phb, float* __restrict__ T, float* __restrict__ R)
{
    constexpr int BM = 128, BN = 64, ST = 40;
    __shared__ unsigned short sA[3][BM * ST];
    __shared__ unsigned short sT[3][BN * ST];
    __shared__ unsigned short sP[3][BN * ST];

    const int tid  = threadIdx.x;
    const int row0 = blockIdx.x * BM;
    const int n0   = blockIdx.y * BN;
    const int lane = tid & 63;
    const int wv   = tid >> 6;
    const int wr   = (wv >> 1) * 64;
    const int wc   = (wv & 1) * 32;
    const int fr   = lane & 15;
    const int fk   = (lane >> 4) * 8;
    const int ar0 = tid >> 2;
    const int ac  = (tid & 3) * 8;

    f32x4 acTh[4][2], acTl[4][2], acQh[4][2], acQl[4][2];
    const f32x4 zz = {0.f, 0.f, 0.f, 0.f};
#pragma unroll
    for (int m = 0; m < 4; ++m)
#pragma unroll
        for (int n = 0; n < 2; ++n) {
            acTh[m][n] = zz; acTl[m][n] = zz;
            acQh[m][n] = zz; acQl[m][n] = zz;
        }

    const float* xA0 = x   + (size_t)(row0 + ar0)      * C + ac;
    const float* xA1 = x   + (size_t)(row0 + 64 + ar0) * C + ac;
    const float* wT  = thw + (size_t)(n0 + ar0)        * C + ac;
    const float* wP  = phw + (size_t)(n0 + ar0)        * C + ac;

    float4 a0a = *(const float4*)(xA0 + 0), a0b = *(const float4*)(xA0 + 4);
    float4 a1a = *(const float4*)(xA1 + 0), a1b = *(const float4*)(xA1 + 4);
    float4 ta  = *(const float4*)(wT  + 0), tb_ = *(const float4*)(wT  + 4);
    float4 pa  = *(const float4*)(wP  + 0), pb_ = *(const float4*)(wP  + 4);

    const int sOffA0 = ar0 * ST + ac;
    const int sOffA1 = (64 + ar0) * ST + ac;
    const int aBase  = (wr + fr) * ST + fk;
    const int bBase  = (wc + fr) * ST + fk;

    for (int step = 0; step < 8; ++step) {
        __syncthreads();
        cvt_store24(sA[0] + sOffA0, sA[1] + sOffA0, sA[2] + sOffA0, a0a, a0b);
        cvt_store24(sA[0] + sOffA1, sA[1] + sOffA1, sA[2] + sOffA1, a1a, a1b);
        cvt_store24(sT[0] + sOffA0, sT[1] + sOffA0, sT[2] + sOffA0, ta,  tb_);
        cvt_store24(sP[0] + sOffA0, sP[1] + sOffA0, sP[2] + sOffA0, pa,  pb_);
        __syncthreads();

        if (step < 7) {
            const int kn = (step + 1) * 32;
            a0a = *(const float4*)(xA0 + kn); a0b = *(const float4*)(xA0 + kn + 4);
            a1a = *(const float4*)(xA1 + kn); a1b = *(const float4*)(xA1 + kn + 4);
            ta  = *(const float4*)(wT  + kn); tb_ = *(const float4*)(wT  + kn + 4);
            pa  = *(const float4*)(wP  + kn); pb_ = *(const float4*)(wP  + kn + 4);
        }

        short8 a1f[4], a2f[4], a3f[4];
#pragma unroll
        for (int m = 0; m < 4; ++m) {
            const int r = aBase + m * 16 * ST;
            a1f[m] = *(const short8*)(sA[0] + r);
            a2f[m] = *(const short8*)(sA[1] + r);
            a3f[m] = *(const short8*)(sA[2] + r);
        }
        {
            short8 t0[2], p0[2];
#pragma unroll
            for (int n = 0; n < 2; ++n) {
                const int r = bBase + n * 16 * ST;
                t0[n] = *(const short8*)(sT[0] + r);
                p0[n] = *(const short8*)(sP[0] + r);
            }
#pragma unroll
            for (int m = 0; m < 4; ++m)
#pragma unroll
                for (int n = 0; n < 2; ++n) {
                    acTh[m][n] = __builtin_amdgcn_mfma_f32_16x16x32_bf16(a1f[m], t0[n], acTh[m][n], 0, 0, 0);
                    acQh[m][n] = __builtin_amdgcn_mfma_f32_16x16x32_bf16(a1f[m], p0[n], acQh[m][n], 0, 0, 0);
                    acTl[m][n] = __builtin_amdgcn_mfma_f32_16x16x32_bf16(a2f[m], t0[n], acTl[m][n], 0, 0, 0);
                    acQl[m][n] = __builtin_amdgcn_mfma_f32_16x16x32_bf16(a2f[m], p0[n], acQl[m][n], 0, 0, 0);
                    acTl[m][n] = __builtin_amdgcn_mfma_f32_16x16x32_bf16(a3f[m], t0[n], acTl[m][n], 0, 0, 0);
                    acQl[m][n] = __builtin_amdgcn_mfma_f32_16x16x32_bf16(a3f[m], p0[n], acQl[m][n], 0, 0, 0);
                }
        }
        {
            short8 t1[2], p1[2];
#pragma unroll
            for (int n = 0; n < 2; ++n) {
                const int r = bBase + n * 16 * ST;
                t1[n] = *(const short8*)(sT[1] + r);
                p1[n] = *(const short8*)(sP[1] + r);
            }
#pragma unroll
            for (int m = 0; m < 4; ++m)
#pragma unroll
                for (int n = 0; n < 2; ++n) {
                    acTl[m][n] = __builtin_amdgcn_mfma_f32_16x16x32_bf16(a1f[m], t1[n], acTl[m][n], 0, 0, 0);
                    acQl[m][n] = __builtin_amdgcn_mfma_f32_16x16x32_bf16(a1f[m], p1[n], acQl[m][n], 0, 0, 0);
                    acTl[m][n] = __builtin_amdgcn_mfma_f32_16x16x32_bf16(a2f[m], t1[n], acTl[m][n], 0, 0, 0);
                    acQl[m][n] = __builtin_amdgcn_mfma_f32_16x16x32_bf16(a2f[m], p1[n], acQl[m][n], 0, 0, 0);
                }
        }
        {
            short8 t2[2], p2[2];
#pragma unroll
            for (int n = 0; n < 2; ++n) {
                const int r = bBase + n * 16 * ST;
                t2[n] = *(const short8*)(sT[2] + r);
                p2[n] = *(const short8*)(sP[2] + r);
            }
#pragma unroll
            for (int m = 0; m < 4; ++m)
#pragma unroll
                for (int n = 0; n < 2; ++n) {
                    acTl[m][n] = __builtin_amdgcn_mfma_f32_16x16x32_bf16(a1f[m], t2[n], acTl[m][n], 0, 0, 0);
                    acQl[m][n] = __builtin_amdgcn_mfma_f32_16x16x32_bf16(a1f[m], p2[n], acQl[m][n], 0, 0, 0);
                }
        }
    }

    const int cr = (lane >> 4) * 4;
#pragma unroll
    for (int m = 0; m < 4; ++m) {
#pragma unroll
        for (int n = 0; n < 2; ++n) {
            const int col  = n0 + wc + n * 16 + fr;
            const float bias = thb[col] + phb[col];
#pragma unroll
            for (int j = 0; j < 4; ++j) {
                const int row = row0 + wr + m * 16 + cr + j;
                const size_t off = (size_t)row * C + col;
                const float tval = acTh[m][n][j] + acTl[m][n][j];
                const float qval = acQh[m][n][j] + acQl[m][n][j];
                T[off] = tval;
                R[off] = x[off] + qval + bias - tval;
            }
        }
    }
}

// ---------------------------------------------------------------------------
// K2ab v2 (fused gather-max + score MLP, 16 nodes/block):
// R13 counters showed the 64-node version was latency-bound at 9.8% occupancy
// (grid 256 = 1 block/CU, VALUBusy 15%, hbm 9%). Same fusion, 4x the blocks:
// grid N/16 = 1024 (4 blocks/CU, ~25KB LDS, 16 waves/CU ~ 50% occupancy).
// Phase 1: per-wave gather (4 nodes/wave, k2a's exact float4/fmax order).
// Phase 2: k2bc's MLP on a 16-row tile -- each (node,out) dot product still
// computed by ONE thread in the SAME ascending k-order => scores and x1
// BIT-IDENTICAL to the R12/R13 PASS. blockIdx&7 = batch -> XCD (T-slab L2).
// ---------------------------------------------------------------------------
__global__ __launch_bounds__(256) void k2ab_fused(
    const int* __restrict__ esrc, const float* __restrict__ T,
    float* __restrict__ x1,
    const float* __restrict__ w1, const float* __restrict__ b1,
    const float* __restrict__ g1, const float* __restrict__ be1,
    const float* __restrict__ m1, const float* __restrict__ v1,
    const float* __restrict__ w2, const float* __restrict__ b2,
    const float* __restrict__ g2, const float* __restrict__ be2,
    const float* __restrict__ m2, const float* __restrict__ v2,
    const float* __restrict__ w3, const float* __restrict__ b3,
    float* __restrict__ score_ws, float* __restrict__ out_score)
{
    constexpr int BK = 16, STW = 68, STX = 17, NB = 16;
    __shared__ float Xs[BK * STX];        // 16 k x 16 rows (+pad)
    __shared__ float Ws[BK * STW];        // 16 k x 64 w1-rows (+pad)
    __shared__ float t1s[NB * 65];
    __shared__ float w2s[32 * 65];
    __shared__ float w3s[32];
    __shared__ float zs[NB * 33];
    __shared__ int eidx[NB][KG];

    const int tid  = threadIdx.x;
    const int bb   = blockIdx.x & 7;                       // batch -> XCD
    const int row0 = bb * N_PER + (blockIdx.x >> 3) * NB;

    // ---- phase 0: stage edge lists (16 nodes x 16 edges, 1/thread) ----
    eidx[tid >> 4][tid & 15] = esrc[(row0 + (tid >> 4)) * KG + (tid & 15)];
    __syncthreads();

    // ---- phase 1: gather-max + R -> x1 (k2a's exact pattern/order) ----
    {
        const int w = tid >> 6, c4 = (tid & 63) * 4;
        for (int it = 0; it < 4; ++it) {
            const int nl = w * 4 + it;
            const int g  = row0 + nl;
            float4 acc = make_float4(-INFINITY, -INFINITY, -INFINITY, -INFINITY);
#pragma unroll
            for (int k = 0; k < KG; ++k) {
                const float4 v = *(const float4*)&T[(size_t)eidx[nl][k] * C + c4];
                acc.x = fmaxf(acc.x, v.x);  acc.y = fmaxf(acc.y, v.y);
                acc.z = fmaxf(acc.z, v.z);  acc.w = fmaxf(acc.w, v.w);
            }
            const size_t off = (size_t)g * C + c4;
            float4 r = *(const float4*)&x1[off];
            r.x += acc.x;  r.y += acc.y;  r.z += acc.z;  r.w += acc.w;
            *(float4*)&x1[off] = r;
        }
    }
    __syncthreads();

    // ---- phase 2: score MLP on 16 rows (same per-dot k-order as k2bc) ----
    const int tx = tid & 15, ty = tid >> 4;     // ty = row 0..15, tx = col-grp
    float acc[4] = {0.f, 0.f, 0.f, 0.f};
    for (int k0 = 0; k0 < C; k0 += BK) {
        // stage Xs: 16 rows x 16 k (threads 0..63, float4)
        // stage Ws: 64 w1-rows x 16 k (all threads, float4)
        float4 fx;
        if (tid < 64)
            fx = *(const float4*)(x1 + (size_t)(row0 + (tid >> 2)) * C + k0 + ((tid & 3) << 2));
        const int lm = tid >> 2, lq = (tid & 3) << 2;
        float4 fw = *(const float4*)(w1 + (size_t)lm * C + k0 + lq);
        __syncthreads();
        if (tid < 64) {
            const int xr = tid >> 2, xq = (tid & 3) << 2;
            Xs[(xq + 0) * STX + xr] = fx.x;  Xs[(xq + 1) * STX + xr] = fx.y;
            Xs[(xq + 2) * STX + xr] = fx.z;  Xs[(xq + 3) * STX + xr] = fx.w;
        }
        Ws[(lq + 0) * STW + lm] = fw.x;  Ws[(lq + 1) * STW + lm] = fw.y;
        Ws[(lq + 2) * STW + lm] = fw.z;  Ws[(lq + 3) * STW + lm] = fw.w;
        __syncthreads();
#pragma unroll
        for (int k = 0; k < BK; ++k) {
            const float av = Xs[k * STX + ty];
            const float4 w4 = *(const float4*)&Ws[k * STW + (tx << 2)];
            acc[0] += av * w4.x;  acc[1] += av * w4.y;
            acc[2] += av * w4.z;  acc[3] += av * w4.w;
        }
    }
    __syncthreads();
#pragma unroll
    for (int j2 = 0; j2 < 4; ++j2) {
        const int o = (tx << 2) + j2;
        float y = acc[j2] + b1[o];
        y = fmaxf(y, 0.f);
        y = (y - m1[o]) * (1.0f / sqrtf(v1[o] + EPS)) * g1[o] + be1[o];
        t1s[ty * 65 + o] = y;
    }
    for (int idx = tid; idx < 2048; idx += 256)
        w2s[(idx >> 6) * 65 + (idx & 63)] = w2[idx];
    if (tid < 32) w3s[tid] = w3[tid];
    __syncthreads();

    const int o = tid & 31;
    const float inv2 = (1.0f / sqrtf(v2[o] + EPS)) * g2[o];
#pragma unroll
    for (int p = 0; p < 2; ++p) {
        const int nl = p * 8 + (tid >> 5);
        float z = 0.f;
#pragma unroll
        for (int j = 0; j < 64; ++j) z += t1s[nl * 65 + j] * w2s[o * 65 + j];
        z += b2[o];
        z = fmaxf(z, 0.f);
        z = (z - m2[o]) * inv2 + be2[o];
        zs[nl * 33 + o] = z;
    }
    __syncthreads();

    if (tid < NB) {
        float sacc = 0.f;
#pragma unroll
        for (int j = 0; j < 32; ++j) sacc += zs[tid * 33 + j] * w3s[j];
        sacc += b3[0];
        const int node = row0 + tid;
        score_ws[node]  = sacc;
        out_score[node] = sacc;
    }
}

// ---------------------------------------------------------------------------
// K3 (rank-select): per-batch top-512, bit-identical to the bitonic version.
// ---------------------------------------------------------------------------
__global__ __launch_bounds__(256) void k3_rank(
    const float* __restrict__ score, const float* __restrict__ xyz,
    float* __restrict__ out_topk, int* __restrict__ perm,
    float* __restrict__ xsel)
{
    __shared__ unsigned long long keys[N_PER];  // 16 KB
    const int b   = blockIdx.x >> 3;
    const int seg = blockIdx.x & 7;
    const int t   = threadIdx.x;
    for (int i = t; i < N_PER; i += 256) {
        const float v = score[b * N_PER + i];
        unsigned u = __float_as_uint(v);
        const unsigned ua = (u & 0x80000000u) ? ~u : (u | 0x80000000u);
        const unsigned ud = ~ua;   // descending-monotone
        keys[i] = ((unsigned long long)ud << 32) | (unsigned)i;
    }
    __syncthreads();
    const int i = seg * 256 + t;
    const unsigned long long k = keys[i];
    int r = 0;
#pragma unroll 8
    for (int j = 0; j < N_PER; ++j) r += (keys[j] < k) ? 1 : 0;
    if (r < KTOP) {
        const int g = b * N_PER + i;
        const int o = b * KTOP + r;
        out_topk[o] = score[g];
        perm[o] = g;
        xsel[o * 3 + 0] = xyz[g * 3 + 0];
        xsel[o * 3 + 1] = xyz[g * 3 + 1];
        xsel[o * 3 + 2] = xyz[g * 3 + 2];
    }
}

// ---------------------------------------------------------------------------
// K5 (wave merge-extract): fused gather + 32-NN, bit-identical output order.
// ---------------------------------------------------------------------------
__device__ inline unsigned long long shfl_xor_u64(unsigned long long v, int m)
{
    unsigned lo = (unsigned)v, hi = (unsigned)(v >> 32);
    lo = __shfl_xor(lo, m, 64);
    hi = __shfl_xor(hi, m, 64);
    return ((unsigned long long)hi << 32) | lo;
}

__global__ __launch_bounds__(256) void k5_rank(
    const int* __restrict__ perm, const float* __restrict__ xsel,
    const float* __restrict__ x1, const float* __restrict__ xorig,
    float* __restrict__ out_xnew, float* __restrict__ out_xcopy,
    float* __restrict__ out_knn)
{
    constexpr int G = 4;
    __shared__ float px[KTOP], py[KTOP], pz[KTOP];
    const int t  = threadIdx.x;
    const int q0 = blockIdx.x * G;
    const int b  = q0 >> 9;
    const int i0 = q0 & 511;

    for (int idx = t; idx < KTOP; idx += 256) {
        const size_t base = ((size_t)b * KTOP + idx) * 3;
        px[idx] = xsel[base + 0];
        py[idx] = xsel[base + 1];
        pz[idx] = xsel[base + 2];
    }
#pragma unroll
    for (int p = 0; p < G; ++p) {
        const int row = q0 + p;
        const int g = perm[row];
        out_xnew [(size_t)row * C + t] = x1   [(size_t)g * C + t];
        out_xcopy[(size_t)row * C + t] = xorig[(size_t)g * C + t];
    }
    __syncthreads();

    const int w    = t >> 6;          // wave id = query slot
    const int lane = t & 63;
    const int q    = i0 + w;          // query index within 512
    const float qx = px[q], qy = py[q], qz = pz[q];

    unsigned long long arr[8];
#pragma unroll
    for (int e = 0; e < 8; ++e) {
        const int j = lane + 64 * e;  // stride-64: conflict-free LDS reads
        const float dx = __fsub_rn(qx, px[j]);
        const float dy = __fsub_rn(qy, py[j]);
        const float dz = __fsub_rn(qz, pz[j]);
        const float d2 = __fadd_rn(__fadd_rn(__fmul_rn(dx, dx), __fmul_rn(dy, dy)),
                                   __fmul_rn(dz, dz));
        arr[e] = ((unsigned long long)__float_as_uint(d2) << 32) | (unsigned)j;
    }
    // sort 8 ascending, fully-unrolled bubble network (const indices -> regs)
#pragma unroll
    for (int pass = 0; pass < 7; ++pass)
#pragma unroll
        for (int i = 0; i < 7; ++i) {
            if (i < 7 - pass) {
                const unsigned long long a = arr[i], c = arr[i + 1];
                arr[i]     = (a < c) ? a : c;
                arr[i + 1] = (a < c) ? c : a;
            }
        }
    // 32 rounds of wave-min merge-extract
    float* dst = out_knn + (size_t)(q0 + w) * KNN;
    for (int r = 0; r < KNN; ++r) {
        unsigned long long m = arr[0];
#pragma unroll
        for (int off = 32; off; off >>= 1) {
            const unsigned long long o = shfl_xor_u64(m, off);
            m = (o < m) ? o : m;
        }
        if (arr[0] == m) {            // unique winner (keys contain idx)
            dst[r] = (float)(unsigned)(m & 0xffffffffu);
#pragma unroll
            for (int i = 0; i < 7; ++i) arr[i] = arr[i + 1];
            arr[7] = ~0ull;           // sentinel
        }
    }
}

// ---------------------------------------------------------------------------
extern "C" void kernel_launch(void* const* d_in, const int* in_sizes, int n_in,
                              void* d_out, int out_size, void* d_ws, size_t ws_size,
                              hipStream_t stream)
{
    const float* x     = (const float*)d_in[0];
    const float* xorig = (const float*)d_in[1];
    const float* xyz   = (const float*)d_in[2];
    const int*   esrc  = (const int*)d_in[3];
    const float* thw = (const float*)d_in[5];
    const float* thb = (const float*)d_in[6];
    const float* phw = (const float*)d_in[7];
    const float* phb = (const float*)d_in[8];
    const float* w1  = (const float*)d_in[9];
    const float* b1  = (const float*)d_in[10];
    const float* g1  = (const float*)d_in[11];
    const float* be1 = (const float*)d_in[12];
    const float* m1  = (const float*)d_in[13];
    const float* v1  = (const float*)d_in[14];
    const float* w2  = (const float*)d_in[15];
    const float* b2  = (const float*)d_in[16];
    const float* g2  = (const float*)d_in[17];
    const float* be2 = (const float*)d_in[18];
    const float* m2  = (const float*)d_in[19];
    const float* v2  = (const float*)d_in[20];
    const float* w3  = (const float*)d_in[21];
    const float* b3  = (const float*)d_in[22];

    float* ws   = (float*)d_ws;
    float* T    = ws;                          // N*C
    float* x1   = ws + (size_t)N * C;          // N*C  (R from k1, becomes x1)
    float* sc   = ws + 2 * (size_t)N * C;      // N
    int*   perm = (int*)(sc + N);              // B*KTOP
    float* xsel = (float*)(perm + B * KTOP);   // B*KTOP*3

    // weight split planes (bf16), 16B-aligned by construction
    unsigned short* th = (unsigned short*)(xsel + (size_t)B * KTOP * 3);
    unsigned short* tm = th + (size_t)C * C;
    unsigned short* tl = tm + (size_t)C * C;
    unsigned short* ph = tl + (size_t)C * C;
    unsigned short* pm = ph + (size_t)C * C;
    unsigned short* pl = pm + (size_t)C * C;
    const size_t ws_need = (size_t)((char*)(pl + (size_t)C * C) - (char*)ws);
    const bool planes_ok = (ws_size >= ws_need);

    float* out     = (float*)d_out;
    float* o_knn   = out;                                  // B*KTOP*KNN
    float* o_xnew  = o_knn + (size_t)B * KTOP * KNN;       // B*KTOP*C
    float* o_xcopy = o_xnew + (size_t)B * KTOP * C;        // B*KTOP*C
    float* o_score = o_xcopy + (size_t)B * KTOP * C;       // B*N_PER
    float* o_topk  = o_score + (size_t)B * N_PER;          // B*KTOP

    if (planes_ok) {
        k0w_split<<<(2 * GW + 255) / 256, 256, 0, stream>>>(
            thw, phw, th, tm, tl, ph, pm, pl);
        k1_wp<<<dim3(N / 128, C / 64), 256, 0, stream>>>(
            x, th, tm, tl, ph, pm, pl, thb, phb, T, x1);
    } else {
        k1_fb<<<dim3(N / 128, C / 64), 256, 0, stream>>>(x, thw, phw, thb, phb, T, x1);
    }
    k2ab_fused<<<N / 16, 256, 0, stream>>>(esrc, T, x1,
                                           w1, b1, g1, be1, m1, v1,
                                           w2, b2, g2, be2, m2, v2, w3, b3,
                                           sc, o_score);
    k3_rank<<<8 * B, 256, 0, stream>>>(sc, xyz, o_topk, perm, xsel);
    k5_rank<<<B * KTOP / 4, 256, 0, stream>>>(perm, xsel, x1, xorig,
                                              o_xnew, o_xcopy, o_knn);
}

// Round 15
// 237.196 us; speedup vs baseline: 1.0723x; 1.0233x over previous
//
#include <hip/hip_runtime.h>
#include <math.h>

// Problem constants (fixed by the reference)
constexpr int B     = 8;
constexpr int N_PER = 2048;
constexpr int C     = 256;
constexpr int KG    = 16;
constexpr int KTOP  = 512;
constexpr int KNN   = 32;
constexpr int N     = B * N_PER;   // 16384
constexpr float EPS = 1e-5f;

typedef __attribute__((ext_vector_type(8))) short  short8;   // 8 bf16 (4 VGPRs)
typedef __attribute__((ext_vector_type(4))) float  f32x4;    // MFMA acc frag

// ---------------------------------------------------------------------------
// Exact 3-way bf16 split: f = h + m + l + O(2^-27 |f|); subtractions exact.
// ---------------------------------------------------------------------------
__device__ inline void split3(float f, unsigned short& h, unsigned short& m,
                              unsigned short& l)
{
    const unsigned u  = __float_as_uint(f);
    const unsigned r1 = (u + 0x7FFFu + ((u >> 16) & 1u)) & 0xFFFF0000u;
    h = (unsigned short)(r1 >> 16);
    const float f2 = f - __uint_as_float(r1);
    const unsigned u2 = __float_as_uint(f2);
    const unsigned r2 = (u2 + 0x7FFFu + ((u2 >> 16) & 1u)) & 0xFFFF0000u;
    m = (unsigned short)(r2 >> 16);
    const float f3 = f2 - __uint_as_float(r2);
    const unsigned u3 = __float_as_uint(f3);
    l = (unsigned short)((u3 + 0x7FFFu + ((u3 >> 16) & 1u)) >> 16);
}

__device__ inline void cvt_store24(unsigned short* dh, unsigned short* dm,
                                   unsigned short* dl, float4 a, float4 b)
{
    short8 h, m, l;
    unsigned short hh, mm, ll;
    float v[8] = {a.x, a.y, a.z, a.w, b.x, b.y, b.z, b.w};
#pragma unroll
    for (int j = 0; j < 8; ++j) {
        split3(v[j], hh, mm, ll);
        h[j] = (short)hh;
        m[j] = (short)mm;
        l[j] = (short)ll;
    }
    *(short8*)dh = h;
    *(short8*)dm = m;
    *(short8*)dl = l;
}

__device__ inline void split8v(const float* __restrict__ s,
                               unsigned short* __restrict__ dh,
                               unsigned short* __restrict__ dm,
                               unsigned short* __restrict__ dl)
{
    float4 a = *(const float4*)s;
    float4 b = *(const float4*)(s + 4);
    float v[8] = {a.x, a.y, a.z, a.w, b.x, b.y, b.z, b.w};
    short8 h8, m8, l8;
    unsigned short hh, mm, ll;
#pragma unroll
    for (int j = 0; j < 8; ++j) {
        split3(v[j], hh, mm, ll);
        h8[j] = (short)hh;
        m8[j] = (short)mm;
        l8[j] = (short)ll;
    }
    *(short8*)dh = h8;
    *(short8*)dm = m8;
    *(short8*)dl = l8;
}

// ---------------------------------------------------------------------------
// K0w: split ONLY the weights into bf16 h/m/l planes (786KB, ~3us).
// ---------------------------------------------------------------------------
constexpr int GW = C * C / 8;    // 8192 groups per weight matrix

__global__ __launch_bounds__(256) void k0w_split(
    const float* __restrict__ thw, const float* __restrict__ phw,
    unsigned short* __restrict__ th, unsigned short* __restrict__ tm,
    unsigned short* __restrict__ tl,
    unsigned short* __restrict__ ph, unsigned short* __restrict__ pm,
    unsigned short* __restrict__ pl)
{
    const int g = blockIdx.x * 256 + threadIdx.x;
    if (g < GW) {
        const int o = g * 8;
        split8v(thw + o, th + o, tm + o, tl + o);
    } else if (g < 2 * GW) {
        const int o = (g - GW) * 8;
        split8v(phw + o, ph + o, pm + o, pl + o);
    }
}

// ---------------------------------------------------------------------------
// K1 v3 (BM=64): R9/R14's k1 was LDS-capped at 2 blocks/CU (61.4KB LDS,
// Occupancy 9%, MfmaUtil 21% + VALUBusy 19% = 60% stall -- barrier drain
// with nothing co-resident to hide it). Halving the row tile: LDS 46.1KB ->
// 3 blocks/CU (12 waves/CU, +50% TLP), grid 512 -> 1024, A-split work per
// thread halves, acc VGPRs halve. Weight planes (768KB) stay L2-resident so
// the doubled strip re-reads are L2-hits (~6us aggregate, overlapped).
// NUMERICS BIT-IDENTICAL: per output element the MFMA sequence (separated
// hi/lo accumulators, ascending-k) is unchanged -- tiling across blocks
// doesn't touch per-element math.
// BM=64 BN=64 BK=32, 4 waves 2x2 (wave tile 32x32), grid (256,4).
// ---------------------------------------------------------------------------
__global__ __launch_bounds__(256) void k1_wp(
    const float* __restrict__ x,
    const unsigned short* __restrict__ th, const unsigned short* __restrict__ tm,
    const unsigned short* __restrict__ tl,
    const unsigned short* __restrict__ ph, const unsigned short* __restrict__ pm,
    const unsigned short* __restrict__ pl,
    const float* __restrict__ thb, const float* __restrict__ phb,
    float* __restrict__ T, float* __restrict__ R)
{
    constexpr int BM = 64, BN = 64, ST = 40;
    __shared__ unsigned short sA[3][BM * ST];
    __shared__ unsigned short sT[3][BN * ST];
    __shared__ unsigned short sP[3][BN * ST];

    const int tid  = threadIdx.x;
    const int row0 = blockIdx.x * BM;
    const int n0   = blockIdx.y * BN;
    const int lane = tid & 63;
    const int wv   = tid >> 6;
    const int wr   = (wv >> 1) * 32;      // wave row offset (2x2 waves, 32x32)
    const int wc   = (wv & 1) * 32;
    const int fr   = lane & 15;
    const int fk   = (lane >> 4) * 8;
    const int ar0  = tid >> 2;            // staging row 0..63
    const int ac   = (tid & 3) * 8;       // staging k-chunk

    f32x4 acTh[2][2], acTl[2][2], acQh[2][2], acQl[2][2];
    const f32x4 zz = {0.f, 0.f, 0.f, 0.f};
#pragma unroll
    for (int m = 0; m < 2; ++m)
#pragma unroll
        for (int n = 0; n < 2; ++n) {
            acTh[m][n] = zz; acTl[m][n] = zz;
            acQh[m][n] = zz; acQl[m][n] = zz;
        }

    const float* xA0 = x + (size_t)(row0 + ar0) * C + ac;
    const size_t offW = (size_t)(n0 + ar0) * C + ac;

    float4 a0a = *(const float4*)(xA0 + 0), a0b = *(const float4*)(xA0 + 4);
    short8 rTh = *(const short8*)(th + offW);
    short8 rTm = *(const short8*)(tm + offW);
    short8 rTl = *(const short8*)(tl + offW);
    short8 rPh = *(const short8*)(ph + offW);
    short8 rPm = *(const short8*)(pm + offW);
    short8 rPl = *(const short8*)(pl + offW);

    const int sOffA0 = ar0 * ST + ac;
    const int aBase  = (wr + fr) * ST + fk;
    const int bBase  = (wc + fr) * ST + fk;

    for (int step = 0; step < 8; ++step) {
        __syncthreads();
        cvt_store24(sA[0] + sOffA0, sA[1] + sOffA0, sA[2] + sOffA0, a0a, a0b);
        *(short8*)(sT[0] + sOffA0) = rTh;
        *(short8*)(sT[1] + sOffA0) = rTm;
        *(short8*)(sT[2] + sOffA0) = rTl;
        *(short8*)(sP[0] + sOffA0) = rPh;
        *(short8*)(sP[1] + sOffA0) = rPm;
        *(short8*)(sP[2] + sOffA0) = rPl;
        __syncthreads();

        if (step < 7) {                    // issue next-tile loads early
            const int kn = (step + 1) * 32;
            a0a = *(const float4*)(xA0 + kn); a0b = *(const float4*)(xA0 + kn + 4);
            rTh = *(const short8*)(th + offW + kn);
            rTm = *(const short8*)(tm + offW + kn);
            rTl = *(const short8*)(tl + offW + kn);
            rPh = *(const short8*)(ph + offW + kn);
            rPm = *(const short8*)(pm + offW + kn);
            rPl = *(const short8*)(pl + offW + kn);
        }

        short8 a1f[2], a2f[2], a3f[2];
#pragma unroll
        for (int m = 0; m < 2; ++m) {
            const int r = aBase + m * 16 * ST;
            a1f[m] = *(const short8*)(sA[0] + r);
            a2f[m] = *(const short8*)(sA[1] + r);
            a3f[m] = *(const short8*)(sA[2] + r);
        }
        {
            short8 t0[2], p0[2];
#pragma unroll
            for (int n = 0; n < 2; ++n) {
                const int r = bBase + n * 16 * ST;
                t0[n] = *(const short8*)(sT[0] + r);
                p0[n] = *(const short8*)(sP[0] + r);
            }
#pragma unroll
            for (int m = 0; m < 2; ++m)
#pragma unroll
                for (int n = 0; n < 2; ++n) {
                    acTh[m][n] = __builtin_amdgcn_mfma_f32_16x16x32_bf16(a1f[m], t0[n], acTh[m][n], 0, 0, 0);
                    acQh[m][n] = __builtin_amdgcn_mfma_f32_16x16x32_bf16(a1f[m], p0[n], acQh[m][n], 0, 0, 0);
                    acTl[m][n] = __builtin_amdgcn_mfma_f32_16x16x32_bf16(a2f[m], t0[n], acTl[m][n], 0, 0, 0);
                    acQl[m][n] = __builtin_amdgcn_mfma_f32_16x16x32_bf16(a2f[m], p0[n], acQl[m][n], 0, 0, 0);
                    acTl[m][n] = __builtin_amdgcn_mfma_f32_16x16x32_bf16(a3f[m], t0[n], acTl[m][n], 0, 0, 0);
                    acQl[m][n] = __builtin_amdgcn_mfma_f32_16x16x32_bf16(a3f[m], p0[n], acQl[m][n], 0, 0, 0);
                }
        }
        {
            short8 t1[2], p1[2];
#pragma unroll
            for (int n = 0; n < 2; ++n) {
                const int r = bBase + n * 16 * ST;
                t1[n] = *(const short8*)(sT[1] + r);
                p1[n] = *(const short8*)(sP[1] + r);
            }
#pragma unroll
            for (int m = 0; m < 2; ++m)
#pragma unroll
                for (int n = 0; n < 2; ++n) {
                    acTl[m][n] = __builtin_amdgcn_mfma_f32_16x16x32_bf16(a1f[m], t1[n], acTl[m][n], 0, 0, 0);
                    acQl[m][n] = __builtin_amdgcn_mfma_f32_16x16x32_bf16(a1f[m], p1[n], acQl[m][n], 0, 0, 0);
                    acTl[m][n] = __builtin_amdgcn_mfma_f32_16x16x32_bf16(a2f[m], t1[n], acTl[m][n], 0, 0, 0);
                    acQl[m][n] = __builtin_amdgcn_mfma_f32_16x16x32_bf16(a2f[m], p1[n], acQl[m][n], 0, 0, 0);
                }
        }
        {
            short8 t2[2], p2[2];
#pragma unroll
            for (int n = 0; n < 2; ++n) {
                const int r = bBase + n * 16 * ST;
                t2[n] = *(const short8*)(sT[2] + r);
                p2[n] = *(const short8*)(sP[2] + r);
            }
#pragma unroll
            for (int m = 0; m < 2; ++m)
#pragma unroll
                for (int n = 0; n < 2; ++n) {
                    acTl[m][n] = __builtin_amdgcn_mfma_f32_16x16x32_bf16(a1f[m], t2[n], acTl[m][n], 0, 0, 0);
                    acQl[m][n] = __builtin_amdgcn_mfma_f32_16x16x32_bf16(a1f[m], p2[n], acQl[m][n], 0, 0, 0);
                }
        }
    }

    const int cr = (lane >> 4) * 4;
#pragma unroll
    for (int m = 0; m < 2; ++m) {
#pragma unroll
        for (int n = 0; n < 2; ++n) {
            const int col  = n0 + wc + n * 16 + fr;
            const float bias = thb[col] + phb[col];
#pragma unroll
            for (int j = 0; j < 4; ++j) {
                const int row = row0 + wr + m * 16 + cr + j;
                const size_t off = (size_t)row * C + col;
                const float tval = acTh[m][n][j] + acTl[m][n][j];
                const float qval = acQh[m][n][j] + acQl[m][n][j];
                T[off] = tval;
                R[off] = x[off] + qval + bias - tval;
            }
        }
    }
}

// ---------------------------------------------------------------------------
// K1 FALLBACK (R5 kernel, BM=128, in-loop weight split): if ws too small.
// ---------------------------------------------------------------------------
__global__ __launch_bounds__(256) void k1_fb(
    const float* __restrict__ x, const float* __restrict__ thw,
    const float* __restrict__ phw, const float* __restrict__ thb,
    const float* __restrict__ phb, float* __restrict__ T, float* __restrict__ R)
{
    constexpr int BM = 128, BN = 64, ST = 40;
    __shared__ unsigned short sA[3][BM * ST];
    __shared__ unsigned short sT[3][BN * ST];
    __shared__ unsigned short sP[3][BN * ST];

    const int tid  = threadIdx.x;
    const int row0 = blockIdx.x * BM;
    const int n0   = blockIdx.y * BN;
    const int lane = tid & 63;
    const int wv   = tid >> 6;
    const int wr   = (wv >> 1) * 64;
    const int wc   = (wv & 1) * 32;
    const int fr   = lane & 15;
    const int fk   = (lane >> 4) * 8;
    const int ar0 = tid >> 2;
    const int ac  = (tid & 3) * 8;

    f32x4 acTh[4][2], acTl[4][2], acQh[4][2], acQl[4][2];
    const f32x4 zz = {0.f, 0.f, 0.f, 0.f};
#pragma unroll
    for (int m = 0; m < 4; ++m)
#pragma unroll
        for (int n = 0; n < 2; ++n) {
            acTh[m][n] = zz; acTl[m][n] = zz;
            acQh[m][n] = zz; acQl[m][n] = zz;
        }

    const float* xA0 = x   + (size_t)(row0 + ar0)      * C + ac;
    const float* xA1 = x   + (size_t)(row0 + 64 + ar0) * C + ac;
    const float* wT  = thw + (size_t)(n0 + ar0)        * C + ac;
    const float* wP  = phw + (size_t)(n0 + ar0)        * C + ac;

    float4 a0a = *(const float4*)(xA0 + 0), a0b = *(const float4*)(xA0 + 4);
    float4 a1a = *(const float4*)(xA1 + 0), a1b = *(const float4*)(xA1 + 4);
    float4 ta  = *(const float4*)(wT  + 0), tb_ = *(const float4*)(wT  + 4);
    float4 pa  = *(const float4*)(wP  + 0), pb_ = *(const float4*)(wP  + 4);

    const int sOffA0 = ar0 * ST + ac;
    const int sOffA1 = (64 + ar0) * ST + ac;
    const int aBase  = (wr + fr) * ST + fk;
    const int bBase  = (wc + fr) * ST + fk;

    for (int step = 0; step < 8; ++step) {
        __syncthreads();
        cvt_store24(sA[0] + sOffA0, sA[1] + sOffA0, sA[2] + sOffA0, a0a, a0b);
        cvt_store24(sA[0] + sOffA1, sA[1] + sOffA1, sA[2] + sOffA1, a1a, a1b);
        cvt_store24(sT[0] + sOffA0, sT[1] + sOffA0, sT[2] + sOffA0, ta,  tb_);
        cvt_store24(sP[0] + sOffA0, sP[1] + sOffA0, sP[2] + sOffA0, pa,  pb_);
        __syncthreads();

        if (step < 7) {
            const int kn = (step + 1) * 32;
            a0a = *(const float4*)(xA0 + kn); a0b = *(const float4*)(xA0 + kn + 4);
            a1a = *(const float4*)(xA1 + kn); a1b = *(const float4*)(xA1 + kn + 4);
            ta  = *(const float4*)(wT  + kn); tb_ = *(const float4*)(wT  + kn + 4);
            pa  = *(const float4*)(wP  + kn); pb_ = *(const float4*)(wP  + kn + 4);
        }

        short8 a1f[4], a2f[4], a3f[4];
#pragma unroll
        for (int m = 0; m < 4; ++m) {
            const int r = aBase + m * 16 * ST;
            a1f[m] = *(const short8*)(sA[0] + r);
            a2f[m] = *(const short8*)(sA[1] + r);
            a3f[m] = *(const short8*)(sA[2] + r);
        }
        {
            short8 t0[2], p0[2];
#pragma unroll
            for (int n = 0; n < 2; ++n) {
                const int r = bBase + n * 16 * ST;
                t0[n] = *(const short8*)(sT[0] + r);
                p0[n] = *(const short8*)(sP[0] + r);
            }
#pragma unroll
            for (int m = 0; m < 4; ++m)
#pragma unroll
                for (int n = 0; n < 2; ++n) {
                    acTh[m][n] = __builtin_amdgcn_mfma_f32_16x16x32_bf16(a1f[m], t0[n], acTh[m][n], 0, 0, 0);
                    acQh[m][n] = __builtin_amdgcn_mfma_f32_16x16x32_bf16(a1f[m], p0[n], acQh[m][n], 0, 0, 0);
                    acTl[m][n] = __builtin_amdgcn_mfma_f32_16x16x32_bf16(a2f[m], t0[n], acTl[m][n], 0, 0, 0);
                    acQl[m][n] = __builtin_amdgcn_mfma_f32_16x16x32_bf16(a2f[m], p0[n], acQl[m][n], 0, 0, 0);
                    acTl[m][n] = __builtin_amdgcn_mfma_f32_16x16x32_bf16(a3f[m], t0[n], acTl[m][n], 0, 0, 0);
                    acQl[m][n] = __builtin_amdgcn_mfma_f32_16x16x32_bf16(a3f[m], p0[n], acQl[m][n], 0, 0, 0);
                }
        }
        {
            short8 t1[2], p1[2];
#pragma unroll
            for (int n = 0; n < 2; ++n) {
                const int r = bBase + n * 16 * ST;
                t1[n] = *(const short8*)(sT[1] + r);
                p1[n] = *(const short8*)(sP[1] + r);
            }
#pragma unroll
            for (int m = 0; m < 4; ++m)
#pragma unroll
                for (int n = 0; n < 2; ++n) {
                    acTl[m][n] = __builtin_amdgcn_mfma_f32_16x16x32_bf16(a1f[m], t1[n], acTl[m][n], 0, 0, 0);
                    acQl[m][n] = __builtin_amdgcn_mfma_f32_16x16x32_bf16(a1f[m], p1[n], acQl[m][n], 0, 0, 0);
                    acTl[m][n] = __builtin_amdgcn_mfma_f32_16x16x32_bf16(a2f[m], t1[n], acTl[m][n], 0, 0, 0);
                    acQl[m][n] = __builtin_amdgcn_mfma_f32_16x16x32_bf16(a2f[m], p1[n], acQl[m][n], 0, 0, 0);
                }
        }
        {
            short8 t2[2], p2[2];
#pragma unroll
            for (int n = 0; n < 2; ++n) {
                const int r = bBase + n * 16 * ST;
                t2[n] = *(const short8*)(sT[2] + r);
                p2[n] = *(const short8*)(sP[2] + r);
            }
#pragma unroll
            for (int m = 0; m < 4; ++m)
#pragma unroll
                for (int n = 0; n < 2; ++n) {
                    acTl[m][n] = __builtin_amdgcn_mfma_f32_16x16x32_bf16(a1f[m], t2[n], acTl[m][n], 0, 0, 0);
                    acQl[m][n] = __builtin_amdgcn_mfma_f32_16x16x32_bf16(a1f[m], p2[n], acQl[m][n], 0, 0, 0);
                }
        }
    }

    const int cr = (lane >> 4) * 4;
#pragma unroll
    for (int m = 0; m < 4; ++m) {
#pragma unroll
        for (int n = 0; n < 2; ++n) {
            const int col  = n0 + wc + n * 16 + fr;
            const float bias = thb[col] + phb[col];
#pragma unroll
            for (int j = 0; j < 4; ++j) {
                const int row = row0 + wr + m * 16 + cr + j;
                const size_t off = (size_t)row * C + col;
                const float tval = acTh[m][n][j] + acTl[m][n][j];
                const float qval = acQh[m][n][j] + acQl[m][n][j];
                T[off] = tval;
                R[off] = x[off] + qval + bias - tval;
            }
        }
    }
}

// ---------------------------------------------------------------------------
// K2ab (fused gather-max + score MLP, 16 nodes/block; R14 PASS, <44us).
// ---------------------------------------------------------------------------
__global__ __launch_bounds__(256) void k2ab_fused(
    const int* __restrict__ esrc, const float* __restrict__ T,
    float* __restrict__ x1,
    const float* __restrict__ w1, const float* __restrict__ b1,
    const float* __restrict__ g1, const float* __restrict__ be1,
    const float* __restrict__ m1, const float* __restrict__ v1,
    const float* __restrict__ w2, const float* __restrict__ b2,
    const float* __restrict__ g2, const float* __restrict__ be2,
    const float* __restrict__ m2, const float* __restrict__ v2,
    const float* __restrict__ w3, const float* __restrict__ b3,
    float* __restrict__ score_ws, float* __restrict__ out_score)
{
    constexpr int BK = 16, STW = 68, STX = 17, NB = 16;
    __shared__ float Xs[BK * STX];
    __shared__ float Ws[BK * STW];
    __shared__ float t1s[NB * 65];
    __shared__ float w2s[32 * 65];
    __shared__ float w3s[32];
    __shared__ float zs[NB * 33];
    __shared__ int eidx[NB][KG];

    const int tid  = threadIdx.x;
    const int bb   = blockIdx.x & 7;                       // batch -> XCD
    const int row0 = bb * N_PER + (blockIdx.x >> 3) * NB;

    eidx[tid >> 4][tid & 15] = esrc[(row0 + (tid >> 4)) * KG + (tid & 15)];
    __syncthreads();

    {
        const int w = tid >> 6, c4 = (tid & 63) * 4;
        for (int it = 0; it < 4; ++it) {
            const int nl = w * 4 + it;
            const int g  = row0 + nl;
            float4 acc = make_float4(-INFINITY, -INFINITY, -INFINITY, -INFINITY);
#pragma unroll
            for (int k = 0; k < KG; ++k) {
                const float4 v = *(const float4*)&T[(size_t)eidx[nl][k] * C + c4];
                acc.x = fmaxf(acc.x, v.x);  acc.y = fmaxf(acc.y, v.y);
                acc.z = fmaxf(acc.z, v.z);  acc.w = fmaxf(acc.w, v.w);
            }
            const size_t off = (size_t)g * C + c4;
            float4 r = *(const float4*)&x1[off];
            r.x += acc.x;  r.y += acc.y;  r.z += acc.z;  r.w += acc.w;
            *(float4*)&x1[off] = r;
        }
    }
    __syncthreads();

    const int tx = tid & 15, ty = tid >> 4;
    float acc[4] = {0.f, 0.f, 0.f, 0.f};
    for (int k0 = 0; k0 < C; k0 += BK) {
        float4 fx;
        if (tid < 64)
            fx = *(const float4*)(x1 + (size_t)(row0 + (tid >> 2)) * C + k0 + ((tid & 3) << 2));
        const int lm = tid >> 2, lq = (tid & 3) << 2;
        float4 fw = *(const float4*)(w1 + (size_t)lm * C + k0 + lq);
        __syncthreads();
        if (tid < 64) {
            const int xr = tid >> 2, xq = (tid & 3) << 2;
            Xs[(xq + 0) * STX + xr] = fx.x;  Xs[(xq + 1) * STX + xr] = fx.y;
            Xs[(xq + 2) * STX + xr] = fx.z;  Xs[(xq + 3) * STX + xr] = fx.w;
        }
        Ws[(lq + 0) * STW + lm] = fw.x;  Ws[(lq + 1) * STW + lm] = fw.y;
        Ws[(lq + 2) * STW + lm] = fw.z;  Ws[(lq + 3) * STW + lm] = fw.w;
        __syncthreads();
#pragma unroll
        for (int k = 0; k < BK; ++k) {
            const float av = Xs[k * STX + ty];
            const float4 w4 = *(const float4*)&Ws[k * STW + (tx << 2)];
            acc[0] += av * w4.x;  acc[1] += av * w4.y;
            acc[2] += av * w4.z;  acc[3] += av * w4.w;
        }
    }
    __syncthreads();
#pragma unroll
    for (int j2 = 0; j2 < 4; ++j2) {
        const int o = (tx << 2) + j2;
        float y = acc[j2] + b1[o];
        y = fmaxf(y, 0.f);
        y = (y - m1[o]) * (1.0f / sqrtf(v1[o] + EPS)) * g1[o] + be1[o];
        t1s[ty * 65 + o] = y;
    }
    for (int idx = tid; idx < 2048; idx += 256)
        w2s[(idx >> 6) * 65 + (idx & 63)] = w2[idx];
    if (tid < 32) w3s[tid] = w3[tid];
    __syncthreads();

    const int o = tid & 31;
    const float inv2 = (1.0f / sqrtf(v2[o] + EPS)) * g2[o];
#pragma unroll
    for (int p = 0; p < 2; ++p) {
        const int nl = p * 8 + (tid >> 5);
        float z = 0.f;
#pragma unroll
        for (int j = 0; j < 64; ++j) z += t1s[nl * 65 + j] * w2s[o * 65 + j];
        z += b2[o];
        z = fmaxf(z, 0.f);
        z = (z - m2[o]) * inv2 + be2[o];
        zs[nl * 33 + o] = z;
    }
    __syncthreads();

    if (tid < NB) {
        float sacc = 0.f;
#pragma unroll
        for (int j = 0; j < 32; ++j) sacc += zs[tid * 33 + j] * w3s[j];
        sacc += b3[0];
        const int node = row0 + tid;
        score_ws[node]  = sacc;
        out_score[node] = sacc;
    }
}

// ---------------------------------------------------------------------------
// K3 (rank-select): per-batch top-512, bit-identical to the bitonic version.
// ---------------------------------------------------------------------------
__global__ __launch_bounds__(256) void k3_rank(
    const float* __restrict__ score, const float* __restrict__ xyz,
    float* __restrict__ out_topk, int* __restrict__ perm,
    float* __restrict__ xsel)
{
    __shared__ unsigned long long keys[N_PER];  // 16 KB
    const int b   = blockIdx.x >> 3;
    const int seg = blockIdx.x & 7;
    const int t   = threadIdx.x;
    for (int i = t; i < N_PER; i += 256) {
        const float v = score[b * N_PER + i];
        unsigned u = __float_as_uint(v);
        const unsigned ua = (u & 0x80000000u) ? ~u : (u | 0x80000000u);
        const unsigned ud = ~ua;   // descending-monotone
        keys[i] = ((unsigned long long)ud << 32) | (unsigned)i;
    }
    __syncthreads();
    const int i = seg * 256 + t;
    const unsigned long long k = keys[i];
    int r = 0;
#pragma unroll 8
    for (int j = 0; j < N_PER; ++j) r += (keys[j] < k) ? 1 : 0;
    if (r < KTOP) {
        const int g = b * N_PER + i;
        const int o = b * KTOP + r;
        out_topk[o] = score[g];
        perm[o] = g;
        xsel[o * 3 + 0] = xyz[g * 3 + 0];
        xsel[o * 3 + 1] = xyz[g * 3 + 1];
        xsel[o * 3 + 2] = xyz[g * 3 + 2];
    }
}

// ---------------------------------------------------------------------------
// K5 (wave merge-extract): fused gather + 32-NN, bit-identical output order.
// ---------------------------------------------------------------------------
__device__ inline unsigned long long shfl_xor_u64(unsigned long long v, int m)
{
    unsigned lo = (unsigned)v, hi = (unsigned)(v >> 32);
    lo = __shfl_xor(lo, m, 64);
    hi = __shfl_xor(hi, m, 64);
    return ((unsigned long long)hi << 32) | lo;
}

__global__ __launch_bounds__(256) void k5_rank(
    const int* __restrict__ perm, const float* __restrict__ xsel,
    const float* __restrict__ x1, const float* __restrict__ xorig,
    float* __restrict__ out_xnew, float* __restrict__ out_xcopy,
    float* __restrict__ out_knn)
{
    constexpr int G = 4;
    __shared__ float px[KTOP], py[KTOP], pz[KTOP];
    const int t  = threadIdx.x;
    const int q0 = blockIdx.x * G;
    const int b  = q0 >> 9;
    const int i0 = q0 & 511;

    for (int idx = t; idx < KTOP; idx += 256) {
        const size_t base = ((size_t)b * KTOP + idx) * 3;
        px[idx] = xsel[base + 0];
        py[idx] = xsel[base + 1];
        pz[idx] = xsel[base + 2];
    }
#pragma unroll
    for (int p = 0; p < G; ++p) {
        const int row = q0 + p;
        const int g = perm[row];
        out_xnew [(size_t)row * C + t] = x1   [(size_t)g * C + t];
        out_xcopy[(size_t)row * C + t] = xorig[(size_t)g * C + t];
    }
    __syncthreads();

    const int w    = t >> 6;
    const int lane = t & 63;
    const int q    = i0 + w;
    const float qx = px[q], qy = py[q], qz = pz[q];

    unsigned long long arr[8];
#pragma unroll
    for (int e = 0; e < 8; ++e) {
        const int j = lane + 64 * e;
        const float dx = __fsub_rn(qx, px[j]);
        const float dy = __fsub_rn(qy, py[j]);
        const float dz = __fsub_rn(qz, pz[j]);
        const float d2 = __fadd_rn(__fadd_rn(__fmul_rn(dx, dx), __fmul_rn(dy, dy)),
                                   __fmul_rn(dz, dz));
        arr[e] = ((unsigned long long)__float_as_uint(d2) << 32) | (unsigned)j;
    }
#pragma unroll
    for (int pass = 0; pass < 7; ++pass)
#pragma unroll
        for (int i = 0; i < 7; ++i) {
            if (i < 7 - pass) {
                const unsigned long long a = arr[i], c = arr[i + 1];
                arr[i]     = (a < c) ? a : c;
                arr[i + 1] = (a < c) ? c : a;
            }
        }
    float* dst = out_knn + (size_t)(q0 + w) * KNN;
    for (int r = 0; r < KNN; ++r) {
        unsigned long long m = arr[0];
#pragma unroll
        for (int off = 32; off; off >>= 1) {
            const unsigned long long o = shfl_xor_u64(m, off);
            m = (o < m) ? o : m;
        }
        if (arr[0] == m) {
            dst[r] = (float)(unsigned)(m & 0xffffffffu);
#pragma unroll
            for (int i = 0; i < 7; ++i) arr[i] = arr[i + 1];
            arr[7] = ~0ull;
        }
    }
}

// ---------------------------------------------------------------------------
extern "C" void kernel_launch(void* const* d_in, const int* in_sizes, int n_in,
                              void* d_out, int out_size, void* d_ws, size_t ws_size,
                              hipStream_t stream)
{
    const float* x     = (const float*)d_in[0];
    const float* xorig = (const float*)d_in[1];
    const float* xyz   = (const float*)d_in[2];
    const int*   esrc  = (const int*)d_in[3];
    const float* thw = (const float*)d_in[5];
    const float* thb = (const float*)d_in[6];
    const float* phw = (const float*)d_in[7];
    const float* phb = (const float*)d_in[8];
    const float* w1  = (const float*)d_in[9];
    const float* b1  = (const float*)d_in[10];
    const float* g1  = (const float*)d_in[11];
    const float* be1 = (const float*)d_in[12];
    const float* m1  = (const float*)d_in[13];
    const float* v1  = (const float*)d_in[14];
    const float* w2  = (const float*)d_in[15];
    const float* b2  = (const float*)d_in[16];
    const float* g2  = (const float*)d_in[17];
    const float* be2 = (const float*)d_in[18];
    const float* m2  = (const float*)d_in[19];
    const float* v2  = (const float*)d_in[20];
    const float* w3  = (const float*)d_in[21];
    const float* b3  = (const float*)d_in[22];

    float* ws   = (float*)d_ws;
    float* T    = ws;                          // N*C
    float* x1   = ws + (size_t)N * C;          // N*C  (R from k1, becomes x1)
    float* sc   = ws + 2 * (size_t)N * C;      // N
    int*   perm = (int*)(sc + N);              // B*KTOP
    float* xsel = (float*)(perm + B * KTOP);   // B*KTOP*3

    // weight split planes (bf16), 16B-aligned by construction
    unsigned short* th = (unsigned short*)(xsel + (size_t)B * KTOP * 3);
    unsigned short* tm = th + (size_t)C * C;
    unsigned short* tl = tm + (size_t)C * C;
    unsigned short* ph = tl + (size_t)C * C;
    unsigned short* pm = ph + (size_t)C * C;
    unsigned short* pl = pm + (size_t)C * C;
    const size_t ws_need = (size_t)((char*)(pl + (size_t)C * C) - (char*)ws);
    const bool planes_ok = (ws_size >= ws_need);

    float* out     = (float*)d_out;
    float* o_knn   = out;                                  // B*KTOP*KNN
    float* o_xnew  = o_knn + (size_t)B * KTOP * KNN;       // B*KTOP*C
    float* o_xcopy = o_xnew + (size_t)B * KTOP * C;        // B*KTOP*C
    float* o_score = o_xcopy + (size_t)B * KTOP * C;       // B*N_PER
    float* o_topk  = o_score + (size_t)B * N_PER;          // B*KTOP

    if (planes_ok) {
        k0w_split<<<(2 * GW + 255) / 256, 256, 0, stream>>>(
            thw, phw, th, tm, tl, ph, pm, pl);
        k1_wp<<<dim3(N / 64, C / 64), 256, 0, stream>>>(
            x, th, tm, tl, ph, pm, pl, thb, phb, T, x1);
    } else {
        k1_fb<<<dim3(N / 128, C / 64), 256, 0, stream>>>(x, thw, phw, thb, phb, T, x1);
    }
    k2ab_fused<<<N / 16, 256, 0, stream>>>(esrc, T, x1,
                                           w1, b1, g1, be1, m1, v1,
                                           w2, b2, g2, be2, m2, v2, w3, b3,
                                           sc, o_score);
    k3_rank<<<8 * B, 256, 0, stream>>>(sc, xyz, o_topk, perm, xsel);
    k5_rank<<<B * KTOP / 4, 256, 0, stream>>>(perm, xsel, x1, xorig,
                                              o_xnew, o_xcopy, o_knn);
}